// Round 14
// baseline (683.394 us; speedup 1.0000x reference)
//
#include <hip/hip_runtime.h>
#include <hip/hip_bf16.h>
#include <stdint.h>

// ---------------------------------------------------------------------------
// Network_60163901882451 — round 28: MS=8 for conv3 (double per-step MFMA).
// r26 post-mortem: MS=2 confounded working-set with per-step work; the
// surviving model is a fixed ~1900cyc per-step wall where only MFMAs-per-
// step moves utilization (r20 up, r26 down). NF is register-maxed; MS 4->8
// at launch_bounds(256,1) (512-reg budget, acc[8][8]=256 AGPRs) gives 64
// MFMAs/step/wave (~1030 issue-cyc) vs the wall -> predicted ~2x util.
// conv3: block = 512 imgs x 128 oc, grid 1296, 1 block/CU. conv2: MS=4
// unchanged. Everything else = r27/r25 best (650.5us).
// ---------------------------------------------------------------------------

#define NIMG 8192
#define NPIX 81
#define FLAT 10368

typedef __hip_bfloat16 bf16;
typedef short bf16x8 __attribute__((ext_vector_type(8)));
typedef float f32x4 __attribute__((ext_vector_type(4)));

__device__ __forceinline__ float bflo(unsigned u) { return __uint_as_float(u << 16); }
__device__ __forceinline__ float bfhi(unsigned u) { return __uint_as_float(u & 0xffff0000u); }
__device__ __forceinline__ unsigned short f2bf(float f) {
    unsigned u = __float_as_uint(f);
    return (unsigned short)((u + 0x7fff + ((u >> 16) & 1)) >> 16);
}

// BN+relu on a bf16x8 fragment; sc/sh are per-element (ci-indexed) registers
__device__ __forceinline__ bf16x8 bn8(bf16x8 a, const float* sc, const float* sh) {
    union U { bf16x8 v; unsigned u[4]; } in, out;
    in.v = a;
#pragma unroll
    for (int d = 0; d < 4; d++) {
        float lo = fmaxf(fmaf(bflo(in.u[d]), sc[2 * d],     sh[2 * d]),     0.f);
        float hi = fmaxf(fmaf(bfhi(in.u[d]), sc[2 * d + 1], sh[2 * d + 1]), 0.f);
        out.u[d] = (unsigned)f2bf(lo) | ((unsigned)f2bf(hi) << 16);
    }
    return out.v;
}

__global__ void fill_sentinel(float* __restrict__ out, int n) {
    int i = blockIdx.x * 256 + threadIdx.x;
    if (i < n) out[i] = 1.0e9f;   // ws_size-too-small signature
}

// ---------------- weight preps ---------------------------------------------
__global__ void prep_w(const float* __restrict__ c1w, const float* __restrict__ c2w,
                       const float* __restrict__ c3w,
                       float* __restrict__ w1t, bf16* __restrict__ w2m,
                       bf16* __restrict__ w3m) {
    int i0 = blockIdx.x * blockDim.x + threadIdx.x;
    int stride = gridDim.x * blockDim.x;
    for (int i = i0; i < 27 * 32; i += stride) w1t[i] = c1w[(i & 31) * 27 + (i >> 5)];
    for (int i = i0; i < 64 * 288; i += stride) {
        int oc = i / 288, r = i - oc * 288, t = r >> 5, ci = r & 31;
        w2m[i] = __float2bfloat16(c2w[oc * 288 + ci * 9 + t]);
    }
    for (int i = i0; i < 128 * 576; i += stride) {
        int oc = i / 576, r = i - oc * 576, t = r >> 6, ci = r & 63;
        w3m[i] = __float2bfloat16(c3w[oc * 576 + ci * 9 + t]);
    }
}

// ewb[e][(px*4+cc)*32+c32] = encw[e][(cc*32+c32)*81+px]  (K-chunk order)
__global__ void prep_enc(const float* __restrict__ encw, bf16* __restrict__ ewb) {
    int i0 = blockIdx.x * blockDim.x + threadIdx.x;
    int stride = gridDim.x * blockDim.x;
    for (int i = i0; i < 128 * FLAT; i += stride) {
        int e = i / FLAT, r = i - e * FLAT;
        int kk = r >> 5, c32 = r & 31;
        int px = kk >> 2, cc = kk & 3;
        ewb[i] = __float2bfloat16(encw[(size_t)e * FLAT + (cc * 32 + c32) * 81 + px]);
    }
}

// --------- one-shot BN+ReLU over a raw activation buffer (in place) --------
// layout [px][ch][img][32]; BN constants computed in-block from raw stats.
template <int NCH>
__global__ __launch_bounds__(256) void bnrelu_k(bf16* __restrict__ x,
        const float* __restrict__ accp, const float* __restrict__ gma,
        const float* __restrict__ bta, int n8) {
    __shared__ float stl[2][NCH * 32];
    int t = threadIdx.x;
    if (t < NCH * 32) {
        const float inv = 1.0f / (8192.0f * 81.0f);
        float mean = accp[t] * inv;
        float var = accp[NCH * 32 + t] * inv - mean * mean;
        float sc = rsqrtf(var + 1e-5f) * gma[t];
        stl[0][t] = sc;
        stl[1][t] = bta[t] - mean * sc;
    }
    __syncthreads();
    int i0 = blockIdx.x * 256 + t;
    int stride = gridDim.x * 256;
    for (int i = i0; i < n8; i += stride) {
        size_t base = (size_t)i * 8;
        int ch = (int)((base >> 18) & (unsigned)(NCH - 1));
        int c0 = ch * 32 + (int)(base & 31);
        float sc[8], sh[8];
#pragma unroll
        for (int j = 0; j < 8; j++) {
            sc[j] = stl[0][c0 + j];
            sh[j] = stl[1][c0 + j];
        }
        bf16x8 v = *(bf16x8*)(x + base);
        *(bf16x8*)(x + base) = bn8(v, sc, sh);
    }
}

// ---------------- conv1 (direct fp32; fused stats; [px][img][32] out) ------
__device__ __forceinline__ void load_row(const float* __restrict__ p, float* r) {
    float4 a = *(const float4*)p;
    float4 b = *(const float4*)(p + 4);
    float4 c = *(const float4*)(p + 8);
    r[0]=a.x; r[1]=a.y; r[2]=a.z;  r[3]=a.w;
    r[4]=b.x; r[5]=b.y; r[6]=b.z;  r[7]=b.w;
    r[8]=c.x; r[9]=c.y; r[10]=c.z; r[11]=c.w;
}

__device__ __forceinline__ void conv_body(const float* __restrict__ inp,
                                          const float* __restrict__ wv, float* acc) {
    float rb[3][12];
    load_row(inp, rb[0]);
    load_row(inp + 12, rb[1]);
#pragma unroll
    for (int oy = 0; oy < 9; oy++) {
        load_row(inp + (oy + 2) * 12, rb[(oy + 2) % 3]);
#pragma unroll
        for (int ky = 0; ky < 3; ky++) {
            const float* r = rb[(oy + ky) % 3];
#pragma unroll
            for (int ox = 0; ox < 9; ox++) {
                float s = acc[oy * 9 + ox];
                s = fmaf(r[ox + 0], wv[ky * 3 + 0], s);
                s = fmaf(r[ox + 1], wv[ky * 3 + 1], s);
                s = fmaf(r[ox + 2], wv[ky * 3 + 2], s);
                acc[oy * 9 + ox] = s;
            }
        }
    }
}

__global__ __launch_bounds__(128) void conv1_kernel(const float* __restrict__ xin,
        const float* __restrict__ wt, const float* __restrict__ bias,
        bf16* __restrict__ xout, float* __restrict__ sacc) {
    __shared__ __align__(16) float lds[4 * 3 * 132];
    __shared__ float Sl[128], Ql[128];
    int t = threadIdx.x;
    int img0 = blockIdx.x * 4;
    for (int i = t; i < 4 * 3 * 132; i += 128) lds[i] = 0.f;
    __syncthreads();
    const float* src = xin + (size_t)img0 * 243;
    for (int i = t; i < 4 * 243; i += 128) {
        int il = i / 243, rem = i - il * 243;
        int ci = rem / 81, px = rem - ci * 81;
        lds[(il * 3 + ci) * 132 + (px / 9 + 1) * 12 + (px % 9) + 1] = src[i];
    }
    __syncthreads();
    int oc = t & 31, il = t >> 5;
    const float* base = lds + il * 3 * 132;
    float acc[81];
    float bb = bias[oc];
#pragma unroll
    for (int i = 0; i < 81; i++) acc[i] = bb;
#pragma unroll
    for (int ci = 0; ci < 3; ci++) {
        float wv[9];
#pragma unroll
        for (int k = 0; k < 9; k++) wv[k] = wt[(ci * 9 + k) * 32 + oc];
        conv_body(base + ci * 132, wv, acc);
    }
    // out: [px][img][32]
    bf16* dst = xout + (size_t)(img0 + il) * 32 + oc;
    const size_t PXS = (size_t)NIMG * 32;
    float s = 0.f, q = 0.f;
#pragma unroll
    for (int p = 0; p < 81; p++) {
        float v = acc[p];
        s += v; q = fmaf(v, v, q);
        dst[p * PXS] = __float2bfloat16(v);
    }
    Sl[il * 32 + oc] = s;
    Ql[il * 32 + oc] = q;
    __syncthreads();
    if (t < 32)
        atomicAdd(&sacc[t], Sl[t] + Sl[32 + t] + Sl[64 + t] + Sl[96 + t]);
    else if (t < 64) {
        int c = t - 32;
        atomicAdd(&sacc[32 + c], Ql[c] + Ql[32 + c] + Ql[64 + c] + Ql[96 + c]);
    }
}

// ------- LDS-staged MFMA conv, pre-BN'd inputs, fused out-stats ------------
// xin: BN+ReLU'd bf16 [81][NCH][NIMG][32]; wm: bf16 [oc][9tap][CI];
// out RAW bf16 [81][NCHO][NIMG][32].
// Block: (MS*64) imgs x NOC oc x 1 pixel; wave = MS 16-img fragments.
// conv2: MS=4 (4 blocks/CU); conv3: MS=8 (acc[8][8]=256 AGPRs, 1 wave/SIMD,
// 64 MFMA/step/wave ~ 1030 issue-cyc vs ~1900cyc step wall).
template <int CI, int COT, int OCS, int MS>
__global__ __launch_bounds__(256, (CI == 64) ? 1 : 4) void conv_tile(
        const bf16* __restrict__ xin,
        const bf16* __restrict__ wm, const float* __restrict__ bias,
        bf16* __restrict__ xout, float* __restrict__ sacc) {
    constexpr int NCH = CI / 32;
    constexpr int NCHO = COT / 32;
    constexpr int NOC = COT / OCS;         // oc per block
    constexpr int NF = NOC / 16;           // oc fragments per block
    constexpr int LNF = (NF == 8) ? 3 : 2;
    constexpr int ROW = 9 * CI;
    constexpr int STEPS = 9 * NCH;
    constexpr int PHASES = STEPS / 9;      // conv2: 1, conv3: 2
    constexpr int HS = STEPS / PHASES;     // 9 steps per phase
    constexpr int IGB = MS * 64;           // imgs per block
    constexpr int GPX = (NIMG / IGB) / 8;  // img groups per XCD
    constexpr size_t CSTRIDE = (size_t)NIMG * 32;   // one (px,ch) slot
    __shared__ bf16 Bs[HS * NF * 64 * 8];
    __shared__ float Ss[2][4][NOC];

    const int lin = blockIdx.x;
    const int xcd = lin & 7;
    const int slot = lin >> 3;
    constexpr int PSL = 81 * OCS;
    const int igl = slot / PSL;
    const int rem = slot - igl * PSL;
    const int p = rem / OCS;
    const int ob = rem - p * OCS;
    const int ig = xcd * GPX + igl;
    const int oc0 = ob * NOC;
    const int py = p / 9, pxx = p - py * 9;
    const int tid = threadIdx.x;
    const int lane = tid & 63, wv = tid >> 6;
    const int m = lane & 15, quad = lane >> 4;
    const long img0 = (long)ig * IGB + wv * (MS * 16);

    int qt[9]; bool vt[9];
#pragma unroll
    for (int t = 0; t < 9; t++) {
        int iy = py + t / 3 - 1, ix = pxx + (t % 3) - 1;
        vt[t] = ((unsigned)iy < 9u) && ((unsigned)ix < 9u);
        qt[t] = vt[t] ? iy * 9 + ix : p;   // clamped safe address
    }

    f32x4 acc[MS][NF];
#pragma unroll
    for (int nf = 0; nf < NF; nf++) {
        float bb = bias[oc0 + nf * 16 + m];
#pragma unroll
        for (int ms = 0; ms < MS; ms++) {
            acc[ms][nf][0] = bb; acc[ms][nf][1] = bb;
            acc[ms][nf][2] = bb; acc[ms][nf][3] = bb;
        }
    }
    // A base: [px][ch][img][32] -> frag = contiguous per wave
    const bf16* ab[MS];
#pragma unroll
    for (int ms = 0; ms < MS; ms++)
        ab[ms] = xin + (img0 + ms * 16 + m) * 32 + quad * 8;

    const bf16* bsl = &Bs[lane * 8];

#pragma unroll
    for (int ph = 0; ph < PHASES; ph++) {
        __syncthreads();
        for (int i = tid; i < HS * NF * 64; i += 256) {
            int l2 = i & 63, nf = (i >> 6) & (NF - 1), sl = i >> (6 + LNF);
            int s = ph * HS + sl;
            int t = s / NCH, ch = s - t * NCH;
            int mm = l2 & 15, qq = l2 >> 4;
            *(bf16x8*)(&Bs[(size_t)i * 8]) =
                *(const bf16x8*)(wm + (size_t)(oc0 + nf * 16 + mm) * ROW + t * CI + ch * 32 + qq * 8);
        }
        __syncthreads();
#pragma unroll
        for (int sl = 0; sl < HS; sl++) {
            const int s = ph * HS + sl;
            const int t = s / NCH, ch = s - t * NCH;
            if (vt[t]) {                     // block-uniform: skip padding taps
                bf16x8 bfr[NF];
#pragma unroll
                for (int nf = 0; nf < NF; nf++)
                    bfr[nf] = *(const bf16x8*)(bsl + (sl * NF + nf) * 512);
                bf16x8 a[MS];
#pragma unroll
                for (int ms = 0; ms < MS; ms++)
                    a[ms] = *(const bf16x8*)(ab[ms] + (size_t)(qt[t] * NCH + ch) * CSTRIDE);
#pragma unroll
                for (int ms = 0; ms < MS; ms++) {
#pragma unroll
                    for (int nf = 0; nf < NF; nf++)
                        acc[ms][nf] = __builtin_amdgcn_mfma_f32_16x16x32_bf16(a[ms], bfr[nf], acc[ms][nf], 0, 0, 0);
                }
            }
        }
    }

    // stores: out[p][chO][img][32]; oc = oc0 + nf*16 + m -> chO = oc0/32+(nf>>1)
    const int och = oc0 >> 5;
#pragma unroll
    for (int ms = 0; ms < MS; ms++)
#pragma unroll
        for (int nf = 0; nf < NF; nf++) {
            bf16* orow = xout
                + (((size_t)p * NCHO + och + (nf >> 1)) * NIMG + img0 + ms * 16 + quad * 4) * 32
                + (nf & 1) * 16 + m;
#pragma unroll
            for (int r = 0; r < 4; r++)
                orow[r * 32] = __float2bfloat16(acc[ms][nf][r]);
        }

    // fused BN stats: per-oc sum / sumsq over this block's outputs
    float ssum[NF], sq[NF];
#pragma unroll
    for (int nf = 0; nf < NF; nf++) {
        float s = 0.f, q = 0.f;
#pragma unroll
        for (int ms = 0; ms < MS; ms++)
#pragma unroll
            for (int r = 0; r < 4; r++) {
                float v = acc[ms][nf][r];
                s += v; q = fmaf(v, v, q);
            }
        s += __shfl_xor(s, 16); s += __shfl_xor(s, 32);
        q += __shfl_xor(q, 16); q += __shfl_xor(q, 32);
        ssum[nf] = s; sq[nf] = q;
    }
    if (lane < 16) {
#pragma unroll
        for (int nf = 0; nf < NF; nf++) {
            Ss[0][wv][nf * 16 + lane] = ssum[nf];
            Ss[1][wv][nf * 16 + lane] = sq[nf];
        }
    }
    __syncthreads();
    if (tid < NOC) {
        float a = Ss[0][0][tid] + Ss[0][1][tid] + Ss[0][2][tid] + Ss[0][3][tid];
        atomicAdd(&sacc[oc0 + tid], a);
    } else if (tid < 2 * NOC) {
        int c = tid - NOC;
        float a = Ss[1][0][c] + Ss[1][1][c] + Ss[1][2][c] + Ss[1][3][c];
        atomicAdd(&sacc[COT + oc0 + c], a);
    }
}

// ----- encoder: x3 = [81][4][NIMG][32]; BN3 constants inline from acc3 -----
// r25: nh-split, grid 512, 2A x 4B frags, B staged in LDS (9-chunk phases).
__global__ __launch_bounds__(256) void enc_mfma(const bf16* __restrict__ x3,
        const bf16* __restrict__ ewb, const float* __restrict__ acc3,
        const float* __restrict__ gma, const float* __restrict__ bta,
        float* __restrict__ part) {
    __shared__ bf16 Bs[9 * 4 * 512];     // 36,864 B: 9 chunks x 4 nf x 512
    const int lin = blockIdx.x;
    const int xcd = lin & 7;
    const int slot = lin >> 3;           // 0..63
    const int igl = slot >> 3;           // 0..7
    const int combo = slot & 7;
    const int ks = combo >> 1, nh = combo & 1;
    const int ig = xcd * 8 + igl;        // 64 groups of 128 imgs
    const int tid = threadIdx.x;
    const int lane = tid & 63, wv = tid >> 6;
    const int m = lane & 15, quad = lane >> 4;
    const long img0 = (long)ig * 128 + wv * 32;
    constexpr size_t CSTRIDE = (size_t)NIMG * 32;

    // BN3 per-lane constants from raw stats (stats_fin folded in)
    const float inv = 1.0f / (8192.0f * 81.0f);
    float scv[4][8], shv[4][8];
#pragma unroll
    for (int cc = 0; cc < 4; cc++)
#pragma unroll
        for (int j = 0; j < 8; j++) {
            int ci = cc * 32 + quad * 8 + j;
            float mean = acc3[ci] * inv;
            float var = acc3[128 + ci] * inv - mean * mean;
            float sc = rsqrtf(var + 1e-5f) * gma[ci];
            scv[cc][j] = sc;
            shv[cc][j] = bta[ci] - mean * sc;
        }

    f32x4 acc[2][4];
#pragma unroll
    for (int ms = 0; ms < 2; ms++)
#pragma unroll
        for (int nf = 0; nf < 4; nf++) {
            acc[ms][nf][0]=0.f; acc[ms][nf][1]=0.f; acc[ms][nf][2]=0.f; acc[ms][nf][3]=0.f;
        }
    const bf16* ab[2];
#pragma unroll
    for (int ms = 0; ms < 2; ms++)
        ab[ms] = x3 + (size_t)(ks * 81) * CSTRIDE + (img0 + ms * 16 + m) * 32 + quad * 8;
    const bf16* bsl = &Bs[lane * 8];

    for (int ph = 0; ph < 9; ph++) {
        __syncthreads();
        // stage 9 chunks x 4 nf x 1KB cooperatively (each elem loaded once/block)
        for (int i = tid; i < 9 * 4 * 64; i += 256) {
            int l2 = i & 63, nf = (i >> 6) & 3, cl = i >> 8;
            int mm = l2 & 15, qq = l2 >> 4;
            *(bf16x8*)(&Bs[(size_t)i * 8]) =
                *(const bf16x8*)(ewb + (size_t)(nh * 64 + nf * 16 + mm) * FLAT
                                 + (ks * 81 + ph * 9 + cl) * 32 + qq * 8);
        }
        __syncthreads();
#pragma unroll
        for (int cl = 0; cl < 9; cl++) {
            const int c = ph * 9 + cl;
            const int cc = (ks + c) & 3;
            bf16x8 Ac[2], Bc[4];
#pragma unroll
            for (int ms = 0; ms < 2; ms++) {
                bf16x8 raw = *(const bf16x8*)(ab[ms] + (size_t)c * CSTRIDE);
                Ac[ms] = bn8(raw, scv[cc], shv[cc]);
            }
#pragma unroll
            for (int nf = 0; nf < 4; nf++)
                Bc[nf] = *(const bf16x8*)(bsl + (cl * 4 + nf) * 512);
#pragma unroll
            for (int nf = 0; nf < 4; nf++)
#pragma unroll
                for (int ms = 0; ms < 2; ms++)
                    acc[ms][nf] = __builtin_amdgcn_mfma_f32_16x16x32_bf16(Ac[ms], Bc[nf], acc[ms][nf], 0, 0, 0);
        }
    }

    float* pp = part + (size_t)ks * (NIMG * 128) + (img0 + quad * 4) * 128 + nh * 64 + m;
#pragma unroll
    for (int ms = 0; ms < 2; ms++)
#pragma unroll
        for (int nf = 0; nf < 4; nf++)
#pragma unroll
            for (int r = 0; r < 4; r++)
                pp[(ms * 16 + r) * 128 + nf * 16] = acc[ms][nf][r];
}

// ---- k-split reduce + bias + transpose: xT[b][f][n] = sum parts + encb ----
__global__ void enc_reduce(const float* __restrict__ part, const float* __restrict__ encb,
                           float* __restrict__ xT) {
    int i = blockIdx.x * 256 + threadIdx.x;
    const int NP = NIMG * 128;
    if (i < NP) {
        float v = part[i] + part[NP + i] + part[2 * NP + i] + part[3 * NP + i] + encb[i & 127];
        int img = i >> 7, f = i & 127;
        xT[(size_t)(img >> 7) * 16384 + f * 128 + (img & 127)] = v;
    }
}

// Y[b] = A[b] (128x128) @ S[b] (128x128); 16-row tiles, grid (8,64)
__global__ __launch_bounds__(256) void mm_xs(const float* __restrict__ A,
        const float* __restrict__ S, float* __restrict__ Y) {
    __shared__ __align__(16) float Sc[32 * 132];
    __shared__ float Acm[16 * 33];
    int b = blockIdx.y, f0 = blockIdx.x * 16;
    int t = threadIdx.x;
    int fl = t & 15, mg = t >> 4;        // fl: row 0..15, mg: col-group of 8
    const float* Ab = A + (size_t)b * 16384;
    const float* Sb = S + (size_t)b * 16384;
    float acc[8];
#pragma unroll
    for (int j = 0; j < 8; j++) acc[j] = 0.f;
    for (int nc = 0; nc < 128; nc += 32) {
#pragma unroll
        for (int r = 0; r < 4; r++) {
            int i4 = r * 256 + t;
            int nn = i4 >> 5, m4 = (i4 & 31) * 4;
            *(float4*)&Sc[nn * 132 + m4] = *(const float4*)&Sb[(size_t)(nc + nn) * 128 + m4];
        }
#pragma unroll
        for (int r = 0; r < 2; r++) {
            int i = r * 256 + t;
            int ff = i >> 5, nn = i & 31;
            Acm[ff * 33 + nn] = Ab[(size_t)(f0 + ff) * 128 + nc + nn];
        }
        __syncthreads();
#pragma unroll 4
        for (int nn = 0; nn < 32; nn++) {
            float a = Acm[fl * 33 + nn];
#pragma unroll
            for (int j = 0; j < 2; j++) {
                float4 s4 = *(const float4*)&Sc[nn * 132 + mg * 8 + j * 4];
                acc[j*4+0] = fmaf(a, s4.x, acc[j*4+0]);
                acc[j*4+1] = fmaf(a, s4.y, acc[j*4+1]);
                acc[j*4+2] = fmaf(a, s4.z, acc[j*4+2]);
                acc[j*4+3] = fmaf(a, s4.w, acc[j*4+3]);
            }
        }
        __syncthreads();
    }
    float* yb = Y + (size_t)b * 16384 + (size_t)(f0 + fl) * 128 + mg * 8;
    *(float4*)&yb[0] = make_float4(acc[0], acc[1], acc[2], acc[3]);
    *(float4*)&yb[4] = make_float4(acc[4], acc[5], acc[6], acc[7]);
}

// Out[b][g][n] = relu( sum_f W0[g,f]Z0 + W1 Z1 + W2 Z2 + bias[g] ); grid (8,64)
__global__ __launch_bounds__(256) void gf_combine(const float* __restrict__ Z0,
        const float* __restrict__ Z1, const float* __restrict__ Z2,
        const float* __restrict__ W, const float* __restrict__ bias,
        float* __restrict__ out) {
    __shared__ __align__(16) float Zc[32 * 132];
    __shared__ float Wc[16 * 33];
    int b = blockIdx.y, g0 = blockIdx.x * 16;
    int t = threadIdx.x;
    int gl = t & 15, mg = t >> 4;
    float acc[8];
    float bb = bias[g0 + gl];
#pragma unroll
    for (int j = 0; j < 8; j++) acc[j] = bb;
    const float* Zs[3] = {Z0 + (size_t)b * 16384, Z1 + (size_t)b * 16384, Z2 + (size_t)b * 16384};
    for (int j3 = 0; j3 < 3; j3++) {
        const float* Zb = Zs[j3];
        const float* Wj = W + j3 * 16384;
        for (int fc = 0; fc < 128; fc += 32) {
#pragma unroll
            for (int r = 0; r < 4; r++) {
                int i4 = r * 256 + t;
                int ff = i4 >> 5, m4 = (i4 & 31) * 4;
                *(float4*)&Zc[ff * 132 + m4] = *(const float4*)&Zb[(size_t)(fc + ff) * 128 + m4];
            }
#pragma unroll
            for (int r = 0; r < 2; r++) {
                int i = r * 256 + t;
                int gg = i >> 5, ff = i & 31;
                Wc[gg * 33 + ff] = Wj[(size_t)(g0 + gg) * 128 + fc + ff];
            }
            __syncthreads();
#pragma unroll 4
            for (int ff = 0; ff < 32; ff++) {
                float w = Wc[gl * 33 + ff];
#pragma unroll
                for (int j = 0; j < 2; j++) {
                    float4 z4 = *(const float4*)&Zc[ff * 132 + mg * 8 + j * 4];
                    acc[j*4+0] = fmaf(w, z4.x, acc[j*4+0]);
                    acc[j*4+1] = fmaf(w, z4.y, acc[j*4+1]);
                    acc[j*4+2] = fmaf(w, z4.z, acc[j*4+2]);
                    acc[j*4+3] = fmaf(w, z4.w, acc[j*4+3]);
                }
            }
            __syncthreads();
        }
    }
    float* ob = out + (size_t)b * 16384 + (size_t)(g0 + gl) * 128 + mg * 8;
    *(float4*)&ob[0] = make_float4(fmaxf(acc[0], 0.f), fmaxf(acc[1], 0.f),
                                   fmaxf(acc[2], 0.f), fmaxf(acc[3], 0.f));
    *(float4*)&ob[4] = make_float4(fmaxf(acc[4], 0.f), fmaxf(acc[5], 0.f),
                                   fmaxf(acc[6], 0.f), fmaxf(acc[7], 0.f));
}

// logits[b,n,a] = sum_g X[b][g][n] * aw[a][g] + ab[a]
__global__ __launch_bounds__(128) void act_kernel(const float* __restrict__ X,
        const float* __restrict__ aw, const float* __restrict__ ab,
        float* __restrict__ out) {
    int b = blockIdx.x, n = threadIdx.x;
    float acc[5];
#pragma unroll
    for (int a = 0; a < 5; a++) acc[a] = ab[a];
    const float* xb = X + (size_t)b * 16384 + n;
#pragma unroll 4
    for (int g = 0; g < 128; g++) {
        float v = xb[(size_t)g * 128];
#pragma unroll
        for (int a = 0; a < 5; a++) acc[a] = fmaf(v, aw[a * 128 + g], acc[a]);
    }
    float* ob = out + ((size_t)b * 128 + n) * 5;
#pragma unroll
    for (int a = 0; a < 5; a++) ob[a] = acc[a];
}

// ---------------------------------------------------------------------------
extern "C" void kernel_launch(void* const* d_in, const int* in_sizes, int n_in,
                              void* d_out, int out_size, void* d_ws, size_t ws_size,
                              hipStream_t stream) {
    const float* states = (const float*)d_in[0];
    const float* gso    = (const float*)d_in[1];
    const float* c1w  = (const float*)d_in[2];
    const float* c1b  = (const float*)d_in[3];
    const float* c1g  = (const float*)d_in[4];
    const float* c1be = (const float*)d_in[5];
    const float* c2w  = (const float*)d_in[6];
    const float* c2b  = (const float*)d_in[7];
    const float* c2g  = (const float*)d_in[8];
    const float* c2be = (const float*)d_in[9];
    const float* c3w  = (const float*)d_in[10];
    const float* c3b  = (const float*)d_in[11];
    const float* c3g  = (const float*)d_in[12];
    const float* c3be = (const float*)d_in[13];
    const float* encw = (const float*)d_in[14];
    const float* encb = (const float*)d_in[15];
    const float* g1w  = (const float*)d_in[16];
    const float* g1b  = (const float*)d_in[17];
    const float* g2w  = (const float*)d_in[18];
    const float* g2b  = (const float*)d_in[19];
    const float* aw   = (const float*)d_in[20];
    const float* ab   = (const float*)d_in[21];
    float* out = (float*)d_out;
    char* ws = (char*)d_ws;

    size_t o = 0;
    auto take = [&](size_t bytes) { size_t r = o; o += (bytes + 255) & ~(size_t)255; return r; };
    const size_t o_x3  = take((size_t)81 * 4 * NIMG * 32 * 2);   // 169,869,312
    const size_t o_x2  = take((size_t)81 * 2 * NIMG * 32 * 2);   //  84,934,656
    const size_t o_w1t = take(27 * 32 * 4);
    const size_t o_w2m = take(64 * 288 * 2);
    const size_t o_w3m = take(128 * 576 * 2);
    const size_t o_acc = take(448 * 4);
    if (ws_size < o) {
        fill_sentinel<<<(out_size + 255) / 256, 256, 0, stream>>>(out, out_size);
        return;
    }

    const size_t o_x1 = o_x3;                       // x1 (42.5MB) at head of x3 region
    const size_t o_ewb  = o_x2;                     // 2,654,208 (aliases dead x2)
    const size_t o_part = o_x2 + 2654208;           // 16,777,216 (4 k-split partials)
    const size_t o_xT   = o_part + 16777216;
    const size_t o_y1   = o_xT + 4194304;
    const size_t o_y2   = o_y1 + 4194304;
    const size_t o_G1   = o_y2 + 4194304;
    const size_t o_G2   = o_G1 + 4194304;           // ends ~40MB < 85MB region

    bf16* x1 = (bf16*)(ws + o_x1);
    bf16* x2 = (bf16*)(ws + o_x2);
    bf16* x3 = (bf16*)(ws + o_x3);
    float* w1t = (float*)(ws + o_w1t);
    bf16* w2m = (bf16*)(ws + o_w2m);
    bf16* w3m = (bf16*)(ws + o_w3m);
    float* acc1 = (float*)(ws + o_acc);
    float* acc2 = acc1 + 64;
    float* acc3 = acc1 + 192;
    bf16* ewb = (bf16*)(ws + o_ewb);
    float* partp = (float*)(ws + o_part);
    float* xT = (float*)(ws + o_xT);
    float* y1 = (float*)(ws + o_y1);
    float* y2 = (float*)(ws + o_y2);
    float* xG1 = (float*)(ws + o_G1);
    float* xG2 = (float*)(ws + o_G2);

    hipMemsetAsync(ws + o_acc, 0, 448 * 4, stream);
    prep_w<<<128, 256, 0, stream>>>(c1w, c2w, c3w, w1t, w2m, w3m);

    conv1_kernel<<<2048, 128, 0, stream>>>(states, w1t, c1b, x1, acc1);
    bnrelu_k<1><<<4096, 256, 0, stream>>>(x1, acc1, c1g, c1be, 81 * 1 * NIMG * 32 / 8);

    conv_tile<32, 64, 1, 4><<<2592, 256, 0, stream>>>(x1, w2m, c2b, x2, acc2);
    bnrelu_k<2><<<4096, 256, 0, stream>>>(x2, acc2, c2g, c2be, 81 * 2 * NIMG * 32 / 8);

    conv_tile<64, 128, 1, 8><<<1296, 256, 0, stream>>>(x2, w3m, c3b, x3, acc3);

    prep_enc<<<2048, 256, 0, stream>>>(encw, ewb);
    enc_mfma<<<512, 256, 0, stream>>>(x3, ewb, acc3, c3g, c3be, partp);
    enc_reduce<<<4096, 256, 0, stream>>>(partp, encb, xT);

    mm_xs<<<dim3(8, 64), 256, 0, stream>>>(xT, gso, y1);
    mm_xs<<<dim3(8, 64), 256, 0, stream>>>(y1, gso, y2);
    gf_combine<<<dim3(8, 64), 256, 0, stream>>>(xT, y1, y2, g1w, g1b, xG1);

    mm_xs<<<dim3(8, 64), 256, 0, stream>>>(xG1, gso, y1);
    mm_xs<<<dim3(8, 64), 256, 0, stream>>>(y1, gso, y2);
    gf_combine<<<dim3(8, 64), 256, 0, stream>>>(xG1, y1, y2, g2w, g2b, xG2);

    act_kernel<<<64, 128, 0, stream>>>(xG2, aw, ab, out);
}

// Round 16
// 654.711 us; speedup vs baseline: 1.0438x; 1.0438x over previous
//
#include <hip/hip_runtime.h>
#include <hip/hip_bf16.h>
#include <stdint.h>

// ---------------------------------------------------------------------------
// Network_60163901882451 — round 30: resubmit of r27/r29 best config
// (650.5us, reproduced twice; r29 bench was an infra failure, not kernel).
// conv_tile r20-shape (MS=4/NF=8 confirmed local optimum), enc_mfma r25
// (B-LDS staging), folded BN stats, 16-row mm/gf retile.
// ---------------------------------------------------------------------------

#define NIMG 8192
#define NPIX 81
#define FLAT 10368

typedef __hip_bfloat16 bf16;
typedef short bf16x8 __attribute__((ext_vector_type(8)));
typedef float f32x4 __attribute__((ext_vector_type(4)));

__device__ __forceinline__ float bflo(unsigned u) { return __uint_as_float(u << 16); }
__device__ __forceinline__ float bfhi(unsigned u) { return __uint_as_float(u & 0xffff0000u); }
__device__ __forceinline__ unsigned short f2bf(float f) {
    unsigned u = __float_as_uint(f);
    return (unsigned short)((u + 0x7fff + ((u >> 16) & 1)) >> 16);
}

// BN+relu on a bf16x8 fragment; sc/sh are per-element (ci-indexed) registers
__device__ __forceinline__ bf16x8 bn8(bf16x8 a, const float* sc, const float* sh) {
    union U { bf16x8 v; unsigned u[4]; } in, out;
    in.v = a;
#pragma unroll
    for (int d = 0; d < 4; d++) {
        float lo = fmaxf(fmaf(bflo(in.u[d]), sc[2 * d],     sh[2 * d]),     0.f);
        float hi = fmaxf(fmaf(bfhi(in.u[d]), sc[2 * d + 1], sh[2 * d + 1]), 0.f);
        out.u[d] = (unsigned)f2bf(lo) | ((unsigned)f2bf(hi) << 16);
    }
    return out.v;
}

__global__ void fill_sentinel(float* __restrict__ out, int n) {
    int i = blockIdx.x * 256 + threadIdx.x;
    if (i < n) out[i] = 1.0e9f;   // ws_size-too-small signature
}

// ---------------- weight preps ---------------------------------------------
__global__ void prep_w(const float* __restrict__ c1w, const float* __restrict__ c2w,
                       const float* __restrict__ c3w,
                       float* __restrict__ w1t, bf16* __restrict__ w2m,
                       bf16* __restrict__ w3m) {
    int i0 = blockIdx.x * blockDim.x + threadIdx.x;
    int stride = gridDim.x * blockDim.x;
    for (int i = i0; i < 27 * 32; i += stride) w1t[i] = c1w[(i & 31) * 27 + (i >> 5)];
    for (int i = i0; i < 64 * 288; i += stride) {
        int oc = i / 288, r = i - oc * 288, t = r >> 5, ci = r & 31;
        w2m[i] = __float2bfloat16(c2w[oc * 288 + ci * 9 + t]);
    }
    for (int i = i0; i < 128 * 576; i += stride) {
        int oc = i / 576, r = i - oc * 576, t = r >> 6, ci = r & 63;
        w3m[i] = __float2bfloat16(c3w[oc * 576 + ci * 9 + t]);
    }
}

// ewb[e][(px*4+cc)*32+c32] = encw[e][(cc*32+c32)*81+px]  (K-chunk order)
__global__ void prep_enc(const float* __restrict__ encw, bf16* __restrict__ ewb) {
    int i0 = blockIdx.x * blockDim.x + threadIdx.x;
    int stride = gridDim.x * blockDim.x;
    for (int i = i0; i < 128 * FLAT; i += stride) {
        int e = i / FLAT, r = i - e * FLAT;
        int kk = r >> 5, c32 = r & 31;
        int px = kk >> 2, cc = kk & 3;
        ewb[i] = __float2bfloat16(encw[(size_t)e * FLAT + (cc * 32 + c32) * 81 + px]);
    }
}

// --------- one-shot BN+ReLU over a raw activation buffer (in place) --------
// layout [px][ch][img][32]; BN constants computed in-block from raw stats.
template <int NCH>
__global__ __launch_bounds__(256) void bnrelu_k(bf16* __restrict__ x,
        const float* __restrict__ accp, const float* __restrict__ gma,
        const float* __restrict__ bta, int n8) {
    __shared__ float stl[2][NCH * 32];
    int t = threadIdx.x;
    if (t < NCH * 32) {
        const float inv = 1.0f / (8192.0f * 81.0f);
        float mean = accp[t] * inv;
        float var = accp[NCH * 32 + t] * inv - mean * mean;
        float sc = rsqrtf(var + 1e-5f) * gma[t];
        stl[0][t] = sc;
        stl[1][t] = bta[t] - mean * sc;
    }
    __syncthreads();
    int i0 = blockIdx.x * 256 + t;
    int stride = gridDim.x * 256;
    for (int i = i0; i < n8; i += stride) {
        size_t base = (size_t)i * 8;
        int ch = (int)((base >> 18) & (unsigned)(NCH - 1));
        int c0 = ch * 32 + (int)(base & 31);
        float sc[8], sh[8];
#pragma unroll
        for (int j = 0; j < 8; j++) {
            sc[j] = stl[0][c0 + j];
            sh[j] = stl[1][c0 + j];
        }
        bf16x8 v = *(bf16x8*)(x + base);
        *(bf16x8*)(x + base) = bn8(v, sc, sh);
    }
}

// ---------------- conv1 (direct fp32; fused stats; [px][img][32] out) ------
__device__ __forceinline__ void load_row(const float* __restrict__ p, float* r) {
    float4 a = *(const float4*)p;
    float4 b = *(const float4*)(p + 4);
    float4 c = *(const float4*)(p + 8);
    r[0]=a.x; r[1]=a.y; r[2]=a.z;  r[3]=a.w;
    r[4]=b.x; r[5]=b.y; r[6]=b.z;  r[7]=b.w;
    r[8]=c.x; r[9]=c.y; r[10]=c.z; r[11]=c.w;
}

__device__ __forceinline__ void conv_body(const float* __restrict__ inp,
                                          const float* __restrict__ wv, float* acc) {
    float rb[3][12];
    load_row(inp, rb[0]);
    load_row(inp + 12, rb[1]);
#pragma unroll
    for (int oy = 0; oy < 9; oy++) {
        load_row(inp + (oy + 2) * 12, rb[(oy + 2) % 3]);
#pragma unroll
        for (int ky = 0; ky < 3; ky++) {
            const float* r = rb[(oy + ky) % 3];
#pragma unroll
            for (int ox = 0; ox < 9; ox++) {
                float s = acc[oy * 9 + ox];
                s = fmaf(r[ox + 0], wv[ky * 3 + 0], s);
                s = fmaf(r[ox + 1], wv[ky * 3 + 1], s);
                s = fmaf(r[ox + 2], wv[ky * 3 + 2], s);
                acc[oy * 9 + ox] = s;
            }
        }
    }
}

__global__ __launch_bounds__(128) void conv1_kernel(const float* __restrict__ xin,
        const float* __restrict__ wt, const float* __restrict__ bias,
        bf16* __restrict__ xout, float* __restrict__ sacc) {
    __shared__ __align__(16) float lds[4 * 3 * 132];
    __shared__ float Sl[128], Ql[128];
    int t = threadIdx.x;
    int img0 = blockIdx.x * 4;
    for (int i = t; i < 4 * 3 * 132; i += 128) lds[i] = 0.f;
    __syncthreads();
    const float* src = xin + (size_t)img0 * 243;
    for (int i = t; i < 4 * 243; i += 128) {
        int il = i / 243, rem = i - il * 243;
        int ci = rem / 81, px = rem - ci * 81;
        lds[(il * 3 + ci) * 132 + (px / 9 + 1) * 12 + (px % 9) + 1] = src[i];
    }
    __syncthreads();
    int oc = t & 31, il = t >> 5;
    const float* base = lds + il * 3 * 132;
    float acc[81];
    float bb = bias[oc];
#pragma unroll
    for (int i = 0; i < 81; i++) acc[i] = bb;
#pragma unroll
    for (int ci = 0; ci < 3; ci++) {
        float wv[9];
#pragma unroll
        for (int k = 0; k < 9; k++) wv[k] = wt[(ci * 9 + k) * 32 + oc];
        conv_body(base + ci * 132, wv, acc);
    }
    // out: [px][img][32]
    bf16* dst = xout + (size_t)(img0 + il) * 32 + oc;
    const size_t PXS = (size_t)NIMG * 32;
    float s = 0.f, q = 0.f;
#pragma unroll
    for (int p = 0; p < 81; p++) {
        float v = acc[p];
        s += v; q = fmaf(v, v, q);
        dst[p * PXS] = __float2bfloat16(v);
    }
    Sl[il * 32 + oc] = s;
    Ql[il * 32 + oc] = q;
    __syncthreads();
    if (t < 32)
        atomicAdd(&sacc[t], Sl[t] + Sl[32 + t] + Sl[64 + t] + Sl[96 + t]);
    else if (t < 64) {
        int c = t - 32;
        atomicAdd(&sacc[32 + c], Ql[c] + Ql[32 + c] + Ql[64 + c] + Ql[96 + c]);
    }
}

// ------- LDS-staged MFMA conv, pre-BN'd inputs, fused out-stats ------------
// xin: BN+ReLU'd bf16 [81][NCH][NIMG][32]; wm: bf16 [oc][9tap][CI];
// out RAW bf16 [81][NCHO][NIMG][32].  (r20 structure — best measured.)
template <int CI, int COT, int OCS>
__global__ __launch_bounds__(256, (CI == 64) ? 2 : 4) void conv_tile(
        const bf16* __restrict__ xin,
        const bf16* __restrict__ wm, const float* __restrict__ bias,
        bf16* __restrict__ xout, float* __restrict__ sacc) {
    constexpr int NCH = CI / 32;
    constexpr int NCHO = COT / 32;
    constexpr int NOC = COT / OCS;         // oc per block
    constexpr int NF = NOC / 16;           // oc fragments per block
    constexpr int LNF = (NF == 8) ? 3 : 2;
    constexpr int ROW = 9 * CI;
    constexpr int STEPS = 9 * NCH;
    constexpr int PHASES = STEPS / 9;      // conv2: 1, conv3: 2
    constexpr int HS = STEPS / PHASES;     // 9 steps per phase
    constexpr size_t CSTRIDE = (size_t)NIMG * 32;   // one (px,ch) slot
    __shared__ bf16 Bs[HS * NF * 64 * 8];
    __shared__ float Ss[2][4][NOC];

    const int lin = blockIdx.x;
    const int xcd = lin & 7;
    const int slot = lin >> 3;
    constexpr int PSL = 81 * OCS;
    const int igl = slot / PSL;
    const int rem = slot - igl * PSL;
    const int p = rem / OCS;
    const int ob = rem - p * OCS;
    const int ig = xcd * 4 + igl;          // 32 groups of 256 imgs
    const int oc0 = ob * NOC;
    const int py = p / 9, pxx = p - py * 9;
    const int tid = threadIdx.x;
    const int lane = tid & 63, wv = tid >> 6;
    const int m = lane & 15, quad = lane >> 4;
    const long img0 = (long)ig * 256 + wv * 64;

    int qt[9]; bool vt[9];
#pragma unroll
    for (int t = 0; t < 9; t++) {
        int iy = py + t / 3 - 1, ix = pxx + (t % 3) - 1;
        vt[t] = ((unsigned)iy < 9u) && ((unsigned)ix < 9u);
        qt[t] = vt[t] ? iy * 9 + ix : p;   // clamped safe address
    }

    f32x4 acc[4][NF];
#pragma unroll
    for (int nf = 0; nf < NF; nf++) {
        float bb = bias[oc0 + nf * 16 + m];
#pragma unroll
        for (int ms = 0; ms < 4; ms++) {
            acc[ms][nf][0] = bb; acc[ms][nf][1] = bb;
            acc[ms][nf][2] = bb; acc[ms][nf][3] = bb;
        }
    }
    // A base: [px][ch][img][32] -> frag = contiguous 1KB per wave
    const bf16* ab[4];
#pragma unroll
    for (int ms = 0; ms < 4; ms++)
        ab[ms] = xin + (img0 + ms * 16 + m) * 32 + quad * 8;

    const bf16* bsl = &Bs[lane * 8];

#pragma unroll
    for (int ph = 0; ph < PHASES; ph++) {
        __syncthreads();
        for (int i = tid; i < HS * NF * 64; i += 256) {
            int l2 = i & 63, nf = (i >> 6) & (NF - 1), sl = i >> (6 + LNF);
            int s = ph * HS + sl;
            int t = s / NCH, ch = s - t * NCH;
            int mm = l2 & 15, qq = l2 >> 4;
            *(bf16x8*)(&Bs[(size_t)i * 8]) =
                *(const bf16x8*)(wm + (size_t)(oc0 + nf * 16 + mm) * ROW + t * CI + ch * 32 + qq * 8);
        }
        __syncthreads();
#pragma unroll
        for (int sl = 0; sl < HS; sl++) {
            const int s = ph * HS + sl;
            const int t = s / NCH, ch = s - t * NCH;
            if (vt[t]) {                     // block-uniform: skip padding taps
                bf16x8 bfr[NF];
#pragma unroll
                for (int nf = 0; nf < NF; nf++)
                    bfr[nf] = *(const bf16x8*)(bsl + (sl * NF + nf) * 512);
                bf16x8 a[4];
#pragma unroll
                for (int ms = 0; ms < 4; ms++)
                    a[ms] = *(const bf16x8*)(ab[ms] + (size_t)(qt[t] * NCH + ch) * CSTRIDE);
#pragma unroll
                for (int ms = 0; ms < 4; ms++) {
#pragma unroll
                    for (int nf = 0; nf < NF; nf++)
                        acc[ms][nf] = __builtin_amdgcn_mfma_f32_16x16x32_bf16(a[ms], bfr[nf], acc[ms][nf], 0, 0, 0);
                }
            }
        }
    }

    // stores: out[p][chO][img][32]; oc = oc0 + nf*16 + m -> chO = oc0/32+(nf>>1)
    const int och = oc0 >> 5;
#pragma unroll
    for (int ms = 0; ms < 4; ms++)
#pragma unroll
        for (int nf = 0; nf < NF; nf++) {
            bf16* orow = xout
                + (((size_t)p * NCHO + och + (nf >> 1)) * NIMG + img0 + ms * 16 + quad * 4) * 32
                + (nf & 1) * 16 + m;
#pragma unroll
            for (int r = 0; r < 4; r++)
                orow[r * 32] = __float2bfloat16(acc[ms][nf][r]);
        }

    // fused BN stats: per-oc sum / sumsq over this block's outputs
    float ssum[NF], sq[NF];
#pragma unroll
    for (int nf = 0; nf < NF; nf++) {
        float s = 0.f, q = 0.f;
#pragma unroll
        for (int ms = 0; ms < 4; ms++)
#pragma unroll
            for (int r = 0; r < 4; r++) {
                float v = acc[ms][nf][r];
                s += v; q = fmaf(v, v, q);
            }
        s += __shfl_xor(s, 16); s += __shfl_xor(s, 32);
        q += __shfl_xor(q, 16); q += __shfl_xor(q, 32);
        ssum[nf] = s; sq[nf] = q;
    }
    if (lane < 16) {
#pragma unroll
        for (int nf = 0; nf < NF; nf++) {
            Ss[0][wv][nf * 16 + lane] = ssum[nf];
            Ss[1][wv][nf * 16 + lane] = sq[nf];
        }
    }
    __syncthreads();
    if (tid < NOC) {
        float a = Ss[0][0][tid] + Ss[0][1][tid] + Ss[0][2][tid] + Ss[0][3][tid];
        atomicAdd(&sacc[oc0 + tid], a);
    } else if (tid < 2 * NOC) {
        int c = tid - NOC;
        float a = Ss[1][0][c] + Ss[1][1][c] + Ss[1][2][c] + Ss[1][3][c];
        atomicAdd(&sacc[COT + oc0 + c], a);
    }
}

// ----- encoder: x3 = [81][4][NIMG][32]; BN3 constants inline from acc3 -----
// r23 decomposition (nh-split, grid 512, 2A x 4B frags) + B staged in LDS:
// all 4 waves read identical ewb fragments -> stage cooperatively in 9-chunk
// phases (36KB, conv_tile's conflict-free layout).
__global__ __launch_bounds__(256) void enc_mfma(const bf16* __restrict__ x3,
        const bf16* __restrict__ ewb, const float* __restrict__ acc3,
        const float* __restrict__ gma, const float* __restrict__ bta,
        float* __restrict__ part) {
    __shared__ bf16 Bs[9 * 4 * 512];     // 36,864 B: 9 chunks x 4 nf x 512
    const int lin = blockIdx.x;
    const int xcd = lin & 7;
    const int slot = lin >> 3;           // 0..63
    const int igl = slot >> 3;           // 0..7
    const int combo = slot & 7;
    const int ks = combo >> 1, nh = combo & 1;
    const int ig = xcd * 8 + igl;        // 64 groups of 128 imgs
    const int tid = threadIdx.x;
    const int lane = tid & 63, wv = tid >> 6;
    const int m = lane & 15, quad = lane >> 4;
    const long img0 = (long)ig * 128 + wv * 32;
    constexpr size_t CSTRIDE = (size_t)NIMG * 32;

    // BN3 per-lane constants from raw stats (stats_fin folded in)
    const float inv = 1.0f / (8192.0f * 81.0f);
    float scv[4][8], shv[4][8];
#pragma unroll
    for (int cc = 0; cc < 4; cc++)
#pragma unroll
        for (int j = 0; j < 8; j++) {
            int ci = cc * 32 + quad * 8 + j;
            float mean = acc3[ci] * inv;
            float var = acc3[128 + ci] * inv - mean * mean;
            float sc = rsqrtf(var + 1e-5f) * gma[ci];
            scv[cc][j] = sc;
            shv[cc][j] = bta[ci] - mean * sc;
        }

    f32x4 acc[2][4];
#pragma unroll
    for (int ms = 0; ms < 2; ms++)
#pragma unroll
        for (int nf = 0; nf < 4; nf++) {
            acc[ms][nf][0]=0.f; acc[ms][nf][1]=0.f; acc[ms][nf][2]=0.f; acc[ms][nf][3]=0.f;
        }
    const bf16* ab[2];
#pragma unroll
    for (int ms = 0; ms < 2; ms++)
        ab[ms] = x3 + (size_t)(ks * 81) * CSTRIDE + (img0 + ms * 16 + m) * 32 + quad * 8;
    const bf16* bsl = &Bs[lane * 8];

    for (int ph = 0; ph < 9; ph++) {
        __syncthreads();
        // stage 9 chunks x 4 nf x 1KB cooperatively (each elem loaded once/block)
        for (int i = tid; i < 9 * 4 * 64; i += 256) {
            int l2 = i & 63, nf = (i >> 6) & 3, cl = i >> 8;
            int mm = l2 & 15, qq = l2 >> 4;
            *(bf16x8*)(&Bs[(size_t)i * 8]) =
                *(const bf16x8*)(ewb + (size_t)(nh * 64 + nf * 16 + mm) * FLAT
                                 + (ks * 81 + ph * 9 + cl) * 32 + qq * 8);
        }
        __syncthreads();
#pragma unroll
        for (int cl = 0; cl < 9; cl++) {
            const int c = ph * 9 + cl;
            const int cc = (ks + c) & 3;
            bf16x8 Ac[2], Bc[4];
#pragma unroll
            for (int ms = 0; ms < 2; ms++) {
                bf16x8 raw = *(const bf16x8*)(ab[ms] + (size_t)c * CSTRIDE);
                Ac[ms] = bn8(raw, scv[cc], shv[cc]);
            }
#pragma unroll
            for (int nf = 0; nf < 4; nf++)
                Bc[nf] = *(const bf16x8*)(bsl + (cl * 4 + nf) * 512);
#pragma unroll
            for (int nf = 0; nf < 4; nf++)
#pragma unroll
                for (int ms = 0; ms < 2; ms++)
                    acc[ms][nf] = __builtin_amdgcn_mfma_f32_16x16x32_bf16(Ac[ms], Bc[nf], acc[ms][nf], 0, 0, 0);
        }
    }

    float* pp = part + (size_t)ks * (NIMG * 128) + (img0 + quad * 4) * 128 + nh * 64 + m;
#pragma unroll
    for (int ms = 0; ms < 2; ms++)
#pragma unroll
        for (int nf = 0; nf < 4; nf++)
#pragma unroll
            for (int r = 0; r < 4; r++)
                pp[(ms * 16 + r) * 128 + nf * 16] = acc[ms][nf][r];
}

// ---- k-split reduce + bias + transpose: xT[b][f][n] = sum parts + encb ----
__global__ void enc_reduce(const float* __restrict__ part, const float* __restrict__ encb,
                           float* __restrict__ xT) {
    int i = blockIdx.x * 256 + threadIdx.x;
    const int NP = NIMG * 128;
    if (i < NP) {
        float v = part[i] + part[NP + i] + part[2 * NP + i] + part[3 * NP + i] + encb[i & 127];
        int img = i >> 7, f = i & 127;
        xT[(size_t)(img >> 7) * 16384 + f * 128 + (img & 127)] = v;
    }
}

// Y[b] = A[b] (128x128) @ S[b] (128x128); 16-row tiles, grid (8,64)
__global__ __launch_bounds__(256) void mm_xs(const float* __restrict__ A,
        const float* __restrict__ S, float* __restrict__ Y) {
    __shared__ __align__(16) float Sc[32 * 132];
    __shared__ float Acm[16 * 33];
    int b = blockIdx.y, f0 = blockIdx.x * 16;
    int t = threadIdx.x;
    int fl = t & 15, mg = t >> 4;        // fl: row 0..15, mg: col-group of 8
    const float* Ab = A + (size_t)b * 16384;
    const float* Sb = S + (size_t)b * 16384;
    float acc[8];
#pragma unroll
    for (int j = 0; j < 8; j++) acc[j] = 0.f;
    for (int nc = 0; nc < 128; nc += 32) {
#pragma unroll
        for (int r = 0; r < 4; r++) {
            int i4 = r * 256 + t;
            int nn = i4 >> 5, m4 = (i4 & 31) * 4;
            *(float4*)&Sc[nn * 132 + m4] = *(const float4*)&Sb[(size_t)(nc + nn) * 128 + m4];
        }
#pragma unroll
        for (int r = 0; r < 2; r++) {
            int i = r * 256 + t;
            int ff = i >> 5, nn = i & 31;
            Acm[ff * 33 + nn] = Ab[(size_t)(f0 + ff) * 128 + nc + nn];
        }
        __syncthreads();
#pragma unroll 4
        for (int nn = 0; nn < 32; nn++) {
            float a = Acm[fl * 33 + nn];
#pragma unroll
            for (int j = 0; j < 2; j++) {
                float4 s4 = *(const float4*)&Sc[nn * 132 + mg * 8 + j * 4];
                acc[j*4+0] = fmaf(a, s4.x, acc[j*4+0]);
                acc[j*4+1] = fmaf(a, s4.y, acc[j*4+1]);
                acc[j*4+2] = fmaf(a, s4.z, acc[j*4+2]);
                acc[j*4+3] = fmaf(a, s4.w, acc[j*4+3]);
            }
        }
        __syncthreads();
    }
    float* yb = Y + (size_t)b * 16384 + (size_t)(f0 + fl) * 128 + mg * 8;
    *(float4*)&yb[0] = make_float4(acc[0], acc[1], acc[2], acc[3]);
    *(float4*)&yb[4] = make_float4(acc[4], acc[5], acc[6], acc[7]);
}

// Out[b][g][n] = relu( sum_f W0[g,f]Z0 + W1 Z1 + W2 Z2 + bias[g] ); grid (8,64)
__global__ __launch_bounds__(256) void gf_combine(const float* __restrict__ Z0,
        const float* __restrict__ Z1, const float* __restrict__ Z2,
        const float* __restrict__ W, const float* __restrict__ bias,
        float* __restrict__ out) {
    __shared__ __align__(16) float Zc[32 * 132];
    __shared__ float Wc[16 * 33];
    int b = blockIdx.y, g0 = blockIdx.x * 16;
    int t = threadIdx.x;
    int gl = t & 15, mg = t >> 4;
    float acc[8];
    float bb = bias[g0 + gl];
#pragma unroll
    for (int j = 0; j < 8; j++) acc[j] = bb;
    const float* Zs[3] = {Z0 + (size_t)b * 16384, Z1 + (size_t)b * 16384, Z2 + (size_t)b * 16384};
    for (int j3 = 0; j3 < 3; j3++) {
        const float* Zb = Zs[j3];
        const float* Wj = W + j3 * 16384;
        for (int fc = 0; fc < 128; fc += 32) {
#pragma unroll
            for (int r = 0; r < 4; r++) {
                int i4 = r * 256 + t;
                int ff = i4 >> 5, m4 = (i4 & 31) * 4;
                *(float4*)&Zc[ff * 132 + m4] = *(const float4*)&Zb[(size_t)(fc + ff) * 128 + m4];
            }
#pragma unroll
            for (int r = 0; r < 2; r++) {
                int i = r * 256 + t;
                int gg = i >> 5, ff = i & 31;
                Wc[gg * 33 + ff] = Wj[(size_t)(g0 + gg) * 128 + fc + ff];
            }
            __syncthreads();
#pragma unroll 4
            for (int ff = 0; ff < 32; ff++) {
                float w = Wc[gl * 33 + ff];
#pragma unroll
                for (int j = 0; j < 2; j++) {
                    float4 z4 = *(const float4*)&Zc[ff * 132 + mg * 8 + j * 4];
                    acc[j*4+0] = fmaf(w, z4.x, acc[j*4+0]);
                    acc[j*4+1] = fmaf(w, z4.y, acc[j*4+1]);
                    acc[j*4+2] = fmaf(w, z4.z, acc[j*4+2]);
                    acc[j*4+3] = fmaf(w, z4.w, acc[j*4+3]);
                }
            }
            __syncthreads();
        }
    }
    float* ob = out + (size_t)b * 16384 + (size_t)(g0 + gl) * 128 + mg * 8;
    *(float4*)&ob[0] = make_float4(fmaxf(acc[0], 0.f), fmaxf(acc[1], 0.f),
                                   fmaxf(acc[2], 0.f), fmaxf(acc[3], 0.f));
    *(float4*)&ob[4] = make_float4(fmaxf(acc[4], 0.f), fmaxf(acc[5], 0.f),
                                   fmaxf(acc[6], 0.f), fmaxf(acc[7], 0.f));
}

// logits[b,n,a] = sum_g X[b][g][n] * aw[a][g] + ab[a]
__global__ __launch_bounds__(128) void act_kernel(const float* __restrict__ X,
        const float* __restrict__ aw, const float* __restrict__ ab,
        float* __restrict__ out) {
    int b = blockIdx.x, n = threadIdx.x;
    float acc[5];
#pragma unroll
    for (int a = 0; a < 5; a++) acc[a] = ab[a];
    const float* xb = X + (size_t)b * 16384 + n;
#pragma unroll 4
    for (int g = 0; g < 128; g++) {
        float v = xb[(size_t)g * 128];
#pragma unroll
        for (int a = 0; a < 5; a++) acc[a] = fmaf(v, aw[a * 128 + g], acc[a]);
    }
    float* ob = out + ((size_t)b * 128 + n) * 5;
#pragma unroll
    for (int a = 0; a < 5; a++) ob[a] = acc[a];
}

// ---------------------------------------------------------------------------
extern "C" void kernel_launch(void* const* d_in, const int* in_sizes, int n_in,
                              void* d_out, int out_size, void* d_ws, size_t ws_size,
                              hipStream_t stream) {
    const float* states = (const float*)d_in[0];
    const float* gso    = (const float*)d_in[1];
    const float* c1w  = (const float*)d_in[2];
    const float* c1b  = (const float*)d_in[3];
    const float* c1g  = (const float*)d_in[4];
    const float* c1be = (const float*)d_in[5];
    const float* c2w  = (const float*)d_in[6];
    const float* c2b  = (const float*)d_in[7];
    const float* c2g  = (const float*)d_in[8];
    const float* c2be = (const float*)d_in[9];
    const float* c3w  = (const float*)d_in[10];
    const float* c3b  = (const float*)d_in[11];
    const float* c3g  = (const float*)d_in[12];
    const float* c3be = (const float*)d_in[13];
    const float* encw = (const float*)d_in[14];
    const float* encb = (const float*)d_in[15];
    const float* g1w  = (const float*)d_in[16];
    const float* g1b  = (const float*)d_in[17];
    const float* g2w  = (const float*)d_in[18];
    const float* g2b  = (const float*)d_in[19];
    const float* aw   = (const float*)d_in[20];
    const float* ab   = (const float*)d_in[21];
    float* out = (float*)d_out;
    char* ws = (char*)d_ws;

    size_t o = 0;
    auto take = [&](size_t bytes) { size_t r = o; o += (bytes + 255) & ~(size_t)255; return r; };
    const size_t o_x3  = take((size_t)81 * 4 * NIMG * 32 * 2);   // 169,869,312
    const size_t o_x2  = take((size_t)81 * 2 * NIMG * 32 * 2);   //  84,934,656
    const size_t o_w1t = take(27 * 32 * 4);
    const size_t o_w2m = take(64 * 288 * 2);
    const size_t o_w3m = take(128 * 576 * 2);
    const size_t o_acc = take(448 * 4);
    if (ws_size < o) {
        fill_sentinel<<<(out_size + 255) / 256, 256, 0, stream>>>(out, out_size);
        return;
    }

    const size_t o_x1 = o_x3;                       // x1 (42.5MB) at head of x3 region
    const size_t o_ewb  = o_x2;                     // 2,654,208 (aliases dead x2)
    const size_t o_part = o_x2 + 2654208;           // 16,777,216 (4 k-split partials)
    const size_t o_xT   = o_part + 16777216;
    const size_t o_y1   = o_xT + 4194304;
    const size_t o_y2   = o_y1 + 4194304;
    const size_t o_G1   = o_y2 + 4194304;
    const size_t o_G2   = o_G1 + 4194304;           // ends ~40MB < 85MB region

    bf16* x1 = (bf16*)(ws + o_x1);
    bf16* x2 = (bf16*)(ws + o_x2);
    bf16* x3 = (bf16*)(ws + o_x3);
    float* w1t = (float*)(ws + o_w1t);
    bf16* w2m = (bf16*)(ws + o_w2m);
    bf16* w3m = (bf16*)(ws + o_w3m);
    float* acc1 = (float*)(ws + o_acc);
    float* acc2 = acc1 + 64;
    float* acc3 = acc1 + 192;
    bf16* ewb = (bf16*)(ws + o_ewb);
    float* partp = (float*)(ws + o_part);
    float* xT = (float*)(ws + o_xT);
    float* y1 = (float*)(ws + o_y1);
    float* y2 = (float*)(ws + o_y2);
    float* xG1 = (float*)(ws + o_G1);
    float* xG2 = (float*)(ws + o_G2);

    hipMemsetAsync(ws + o_acc, 0, 448 * 4, stream);
    prep_w<<<128, 256, 0, stream>>>(c1w, c2w, c3w, w1t, w2m, w3m);

    conv1_kernel<<<2048, 128, 0, stream>>>(states, w1t, c1b, x1, acc1);
    bnrelu_k<1><<<4096, 256, 0, stream>>>(x1, acc1, c1g, c1be, 81 * 1 * NIMG * 32 / 8);

    conv_tile<32, 64, 1><<<2592, 256, 0, stream>>>(x1, w2m, c2b, x2, acc2);
    bnrelu_k<2><<<4096, 256, 0, stream>>>(x2, acc2, c2g, c2be, 81 * 2 * NIMG * 32 / 8);

    conv_tile<64, 128, 1><<<2592, 256, 0, stream>>>(x2, w3m, c3b, x3, acc3);

    prep_enc<<<2048, 256, 0, stream>>>(encw, ewb);
    enc_mfma<<<512, 256, 0, stream>>>(x3, ewb, acc3, c3g, c3be, partp);
    enc_reduce<<<4096, 256, 0, stream>>>(partp, encb, xT);

    mm_xs<<<dim3(8, 64), 256, 0, stream>>>(xT, gso, y1);
    mm_xs<<<dim3(8, 64), 256, 0, stream>>>(y1, gso, y2);
    gf_combine<<<dim3(8, 64), 256, 0, stream>>>(xT, y1, y2, g1w, g1b, xG1);

    mm_xs<<<dim3(8, 64), 256, 0, stream>>>(xG1, gso, y1);
    mm_xs<<<dim3(8, 64), 256, 0, stream>>>(y1, gso, y2);
    gf_combine<<<dim3(8, 64), 256, 0, stream>>>(xG1, y1, y2, g2w, g2b, xG2);

    act_kernel<<<64, 128, 0, stream>>>(xG2, aw, ab, out);
}

// Round 17
// 643.455 us; speedup vs baseline: 1.0621x; 1.0175x over previous
//
#include <hip/hip_runtime.h>
#include <hip/hip_bf16.h>
#include <stdint.h>

// ---------------------------------------------------------------------------
// Network_60163901882451 — round 31: r27 best config + isolated act_kernel
// parallelization (the one r24 change never tested alone). act was 64 blocks
// on 256 CUs with a 128-iter serial strided-load chain. Now: grid (64,4),
// 128 thr = 32 n x 4 g-chunks, LDS reduce, gs==0 writes + bias. No atomics,
// no memset, deterministic. Everything else identical to the 650.5us state.
// ---------------------------------------------------------------------------

#define NIMG 8192
#define NPIX 81
#define FLAT 10368

typedef __hip_bfloat16 bf16;
typedef short bf16x8 __attribute__((ext_vector_type(8)));
typedef float f32x4 __attribute__((ext_vector_type(4)));

__device__ __forceinline__ float bflo(unsigned u) { return __uint_as_float(u << 16); }
__device__ __forceinline__ float bfhi(unsigned u) { return __uint_as_float(u & 0xffff0000u); }
__device__ __forceinline__ unsigned short f2bf(float f) {
    unsigned u = __float_as_uint(f);
    return (unsigned short)((u + 0x7fff + ((u >> 16) & 1)) >> 16);
}

// BN+relu on a bf16x8 fragment; sc/sh are per-element (ci-indexed) registers
__device__ __forceinline__ bf16x8 bn8(bf16x8 a, const float* sc, const float* sh) {
    union U { bf16x8 v; unsigned u[4]; } in, out;
    in.v = a;
#pragma unroll
    for (int d = 0; d < 4; d++) {
        float lo = fmaxf(fmaf(bflo(in.u[d]), sc[2 * d],     sh[2 * d]),     0.f);
        float hi = fmaxf(fmaf(bfhi(in.u[d]), sc[2 * d + 1], sh[2 * d + 1]), 0.f);
        out.u[d] = (unsigned)f2bf(lo) | ((unsigned)f2bf(hi) << 16);
    }
    return out.v;
}

__global__ void fill_sentinel(float* __restrict__ out, int n) {
    int i = blockIdx.x * 256 + threadIdx.x;
    if (i < n) out[i] = 1.0e9f;   // ws_size-too-small signature
}

// ---------------- weight preps ---------------------------------------------
__global__ void prep_w(const float* __restrict__ c1w, const float* __restrict__ c2w,
                       const float* __restrict__ c3w,
                       float* __restrict__ w1t, bf16* __restrict__ w2m,
                       bf16* __restrict__ w3m) {
    int i0 = blockIdx.x * blockDim.x + threadIdx.x;
    int stride = gridDim.x * blockDim.x;
    for (int i = i0; i < 27 * 32; i += stride) w1t[i] = c1w[(i & 31) * 27 + (i >> 5)];
    for (int i = i0; i < 64 * 288; i += stride) {
        int oc = i / 288, r = i - oc * 288, t = r >> 5, ci = r & 31;
        w2m[i] = __float2bfloat16(c2w[oc * 288 + ci * 9 + t]);
    }
    for (int i = i0; i < 128 * 576; i += stride) {
        int oc = i / 576, r = i - oc * 576, t = r >> 6, ci = r & 63;
        w3m[i] = __float2bfloat16(c3w[oc * 576 + ci * 9 + t]);
    }
}

// ewb[e][(px*4+cc)*32+c32] = encw[e][(cc*32+c32)*81+px]  (K-chunk order)
__global__ void prep_enc(const float* __restrict__ encw, bf16* __restrict__ ewb) {
    int i0 = blockIdx.x * blockDim.x + threadIdx.x;
    int stride = gridDim.x * blockDim.x;
    for (int i = i0; i < 128 * FLAT; i += stride) {
        int e = i / FLAT, r = i - e * FLAT;
        int kk = r >> 5, c32 = r & 31;
        int px = kk >> 2, cc = kk & 3;
        ewb[i] = __float2bfloat16(encw[(size_t)e * FLAT + (cc * 32 + c32) * 81 + px]);
    }
}

// --------- one-shot BN+ReLU over a raw activation buffer (in place) --------
// layout [px][ch][img][32]; BN constants computed in-block from raw stats.
template <int NCH>
__global__ __launch_bounds__(256) void bnrelu_k(bf16* __restrict__ x,
        const float* __restrict__ accp, const float* __restrict__ gma,
        const float* __restrict__ bta, int n8) {
    __shared__ float stl[2][NCH * 32];
    int t = threadIdx.x;
    if (t < NCH * 32) {
        const float inv = 1.0f / (8192.0f * 81.0f);
        float mean = accp[t] * inv;
        float var = accp[NCH * 32 + t] * inv - mean * mean;
        float sc = rsqrtf(var + 1e-5f) * gma[t];
        stl[0][t] = sc;
        stl[1][t] = bta[t] - mean * sc;
    }
    __syncthreads();
    int i0 = blockIdx.x * 256 + t;
    int stride = gridDim.x * 256;
    for (int i = i0; i < n8; i += stride) {
        size_t base = (size_t)i * 8;
        int ch = (int)((base >> 18) & (unsigned)(NCH - 1));
        int c0 = ch * 32 + (int)(base & 31);
        float sc[8], sh[8];
#pragma unroll
        for (int j = 0; j < 8; j++) {
            sc[j] = stl[0][c0 + j];
            sh[j] = stl[1][c0 + j];
        }
        bf16x8 v = *(bf16x8*)(x + base);
        *(bf16x8*)(x + base) = bn8(v, sc, sh);
    }
}

// ---------------- conv1 (direct fp32; fused stats; [px][img][32] out) ------
__device__ __forceinline__ void load_row(const float* __restrict__ p, float* r) {
    float4 a = *(const float4*)p;
    float4 b = *(const float4*)(p + 4);
    float4 c = *(const float4*)(p + 8);
    r[0]=a.x; r[1]=a.y; r[2]=a.z;  r[3]=a.w;
    r[4]=b.x; r[5]=b.y; r[6]=b.z;  r[7]=b.w;
    r[8]=c.x; r[9]=c.y; r[10]=c.z; r[11]=c.w;
}

__device__ __forceinline__ void conv_body(const float* __restrict__ inp,
                                          const float* __restrict__ wv, float* acc) {
    float rb[3][12];
    load_row(inp, rb[0]);
    load_row(inp + 12, rb[1]);
#pragma unroll
    for (int oy = 0; oy < 9; oy++) {
        load_row(inp + (oy + 2) * 12, rb[(oy + 2) % 3]);
#pragma unroll
        for (int ky = 0; ky < 3; ky++) {
            const float* r = rb[(oy + ky) % 3];
#pragma unroll
            for (int ox = 0; ox < 9; ox++) {
                float s = acc[oy * 9 + ox];
                s = fmaf(r[ox + 0], wv[ky * 3 + 0], s);
                s = fmaf(r[ox + 1], wv[ky * 3 + 1], s);
                s = fmaf(r[ox + 2], wv[ky * 3 + 2], s);
                acc[oy * 9 + ox] = s;
            }
        }
    }
}

__global__ __launch_bounds__(128) void conv1_kernel(const float* __restrict__ xin,
        const float* __restrict__ wt, const float* __restrict__ bias,
        bf16* __restrict__ xout, float* __restrict__ sacc) {
    __shared__ __align__(16) float lds[4 * 3 * 132];
    __shared__ float Sl[128], Ql[128];
    int t = threadIdx.x;
    int img0 = blockIdx.x * 4;
    for (int i = t; i < 4 * 3 * 132; i += 128) lds[i] = 0.f;
    __syncthreads();
    const float* src = xin + (size_t)img0 * 243;
    for (int i = t; i < 4 * 243; i += 128) {
        int il = i / 243, rem = i - il * 243;
        int ci = rem / 81, px = rem - ci * 81;
        lds[(il * 3 + ci) * 132 + (px / 9 + 1) * 12 + (px % 9) + 1] = src[i];
    }
    __syncthreads();
    int oc = t & 31, il = t >> 5;
    const float* base = lds + il * 3 * 132;
    float acc[81];
    float bb = bias[oc];
#pragma unroll
    for (int i = 0; i < 81; i++) acc[i] = bb;
#pragma unroll
    for (int ci = 0; ci < 3; ci++) {
        float wv[9];
#pragma unroll
        for (int k = 0; k < 9; k++) wv[k] = wt[(ci * 9 + k) * 32 + oc];
        conv_body(base + ci * 132, wv, acc);
    }
    // out: [px][img][32]
    bf16* dst = xout + (size_t)(img0 + il) * 32 + oc;
    const size_t PXS = (size_t)NIMG * 32;
    float s = 0.f, q = 0.f;
#pragma unroll
    for (int p = 0; p < 81; p++) {
        float v = acc[p];
        s += v; q = fmaf(v, v, q);
        dst[p * PXS] = __float2bfloat16(v);
    }
    Sl[il * 32 + oc] = s;
    Ql[il * 32 + oc] = q;
    __syncthreads();
    if (t < 32)
        atomicAdd(&sacc[t], Sl[t] + Sl[32 + t] + Sl[64 + t] + Sl[96 + t]);
    else if (t < 64) {
        int c = t - 32;
        atomicAdd(&sacc[32 + c], Ql[c] + Ql[32 + c] + Ql[64 + c] + Ql[96 + c]);
    }
}

// ------- LDS-staged MFMA conv, pre-BN'd inputs, fused out-stats ------------
// xin: BN+ReLU'd bf16 [81][NCH][NIMG][32]; wm: bf16 [oc][9tap][CI];
// out RAW bf16 [81][NCHO][NIMG][32].  (r20 structure — best measured.)
template <int CI, int COT, int OCS>
__global__ __launch_bounds__(256, (CI == 64) ? 2 : 4) void conv_tile(
        const bf16* __restrict__ xin,
        const bf16* __restrict__ wm, const float* __restrict__ bias,
        bf16* __restrict__ xout, float* __restrict__ sacc) {
    constexpr int NCH = CI / 32;
    constexpr int NCHO = COT / 32;
    constexpr int NOC = COT / OCS;         // oc per block
    constexpr int NF = NOC / 16;           // oc fragments per block
    constexpr int LNF = (NF == 8) ? 3 : 2;
    constexpr int ROW = 9 * CI;
    constexpr int STEPS = 9 * NCH;
    constexpr int PHASES = STEPS / 9;      // conv2: 1, conv3: 2
    constexpr int HS = STEPS / PHASES;     // 9 steps per phase
    constexpr size_t CSTRIDE = (size_t)NIMG * 32;   // one (px,ch) slot
    __shared__ bf16 Bs[HS * NF * 64 * 8];
    __shared__ float Ss[2][4][NOC];

    const int lin = blockIdx.x;
    const int xcd = lin & 7;
    const int slot = lin >> 3;
    constexpr int PSL = 81 * OCS;
    const int igl = slot / PSL;
    const int rem = slot - igl * PSL;
    const int p = rem / OCS;
    const int ob = rem - p * OCS;
    const int ig = xcd * 4 + igl;          // 32 groups of 256 imgs
    const int oc0 = ob * NOC;
    const int py = p / 9, pxx = p - py * 9;
    const int tid = threadIdx.x;
    const int lane = tid & 63, wv = tid >> 6;
    const int m = lane & 15, quad = lane >> 4;
    const long img0 = (long)ig * 256 + wv * 64;

    int qt[9]; bool vt[9];
#pragma unroll
    for (int t = 0; t < 9; t++) {
        int iy = py + t / 3 - 1, ix = pxx + (t % 3) - 1;
        vt[t] = ((unsigned)iy < 9u) && ((unsigned)ix < 9u);
        qt[t] = vt[t] ? iy * 9 + ix : p;   // clamped safe address
    }

    f32x4 acc[4][NF];
#pragma unroll
    for (int nf = 0; nf < NF; nf++) {
        float bb = bias[oc0 + nf * 16 + m];
#pragma unroll
        for (int ms = 0; ms < 4; ms++) {
            acc[ms][nf][0] = bb; acc[ms][nf][1] = bb;
            acc[ms][nf][2] = bb; acc[ms][nf][3] = bb;
        }
    }
    // A base: [px][ch][img][32] -> frag = contiguous 1KB per wave
    const bf16* ab[4];
#pragma unroll
    for (int ms = 0; ms < 4; ms++)
        ab[ms] = xin + (img0 + ms * 16 + m) * 32 + quad * 8;

    const bf16* bsl = &Bs[lane * 8];

#pragma unroll
    for (int ph = 0; ph < PHASES; ph++) {
        __syncthreads();
        for (int i = tid; i < HS * NF * 64; i += 256) {
            int l2 = i & 63, nf = (i >> 6) & (NF - 1), sl = i >> (6 + LNF);
            int s = ph * HS + sl;
            int t = s / NCH, ch = s - t * NCH;
            int mm = l2 & 15, qq = l2 >> 4;
            *(bf16x8*)(&Bs[(size_t)i * 8]) =
                *(const bf16x8*)(wm + (size_t)(oc0 + nf * 16 + mm) * ROW + t * CI + ch * 32 + qq * 8);
        }
        __syncthreads();
#pragma unroll
        for (int sl = 0; sl < HS; sl++) {
            const int s = ph * HS + sl;
            const int t = s / NCH, ch = s - t * NCH;
            if (vt[t]) {                     // block-uniform: skip padding taps
                bf16x8 bfr[NF];
#pragma unroll
                for (int nf = 0; nf < NF; nf++)
                    bfr[nf] = *(const bf16x8*)(bsl + (sl * NF + nf) * 512);
                bf16x8 a[4];
#pragma unroll
                for (int ms = 0; ms < 4; ms++)
                    a[ms] = *(const bf16x8*)(ab[ms] + (size_t)(qt[t] * NCH + ch) * CSTRIDE);
#pragma unroll
                for (int ms = 0; ms < 4; ms++) {
#pragma unroll
                    for (int nf = 0; nf < NF; nf++)
                        acc[ms][nf] = __builtin_amdgcn_mfma_f32_16x16x32_bf16(a[ms], bfr[nf], acc[ms][nf], 0, 0, 0);
                }
            }
        }
    }

    // stores: out[p][chO][img][32]; oc = oc0 + nf*16 + m -> chO = oc0/32+(nf>>1)
    const int och = oc0 >> 5;
#pragma unroll
    for (int ms = 0; ms < 4; ms++)
#pragma unroll
        for (int nf = 0; nf < NF; nf++) {
            bf16* orow = xout
                + (((size_t)p * NCHO + och + (nf >> 1)) * NIMG + img0 + ms * 16 + quad * 4) * 32
                + (nf & 1) * 16 + m;
#pragma unroll
            for (int r = 0; r < 4; r++)
                orow[r * 32] = __float2bfloat16(acc[ms][nf][r]);
        }

    // fused BN stats: per-oc sum / sumsq over this block's outputs
    float ssum[NF], sq[NF];
#pragma unroll
    for (int nf = 0; nf < NF; nf++) {
        float s = 0.f, q = 0.f;
#pragma unroll
        for (int ms = 0; ms < 4; ms++)
#pragma unroll
            for (int r = 0; r < 4; r++) {
                float v = acc[ms][nf][r];
                s += v; q = fmaf(v, v, q);
            }
        s += __shfl_xor(s, 16); s += __shfl_xor(s, 32);
        q += __shfl_xor(q, 16); q += __shfl_xor(q, 32);
        ssum[nf] = s; sq[nf] = q;
    }
    if (lane < 16) {
#pragma unroll
        for (int nf = 0; nf < NF; nf++) {
            Ss[0][wv][nf * 16 + lane] = ssum[nf];
            Ss[1][wv][nf * 16 + lane] = sq[nf];
        }
    }
    __syncthreads();
    if (tid < NOC) {
        float a = Ss[0][0][tid] + Ss[0][1][tid] + Ss[0][2][tid] + Ss[0][3][tid];
        atomicAdd(&sacc[oc0 + tid], a);
    } else if (tid < 2 * NOC) {
        int c = tid - NOC;
        float a = Ss[1][0][c] + Ss[1][1][c] + Ss[1][2][c] + Ss[1][3][c];
        atomicAdd(&sacc[COT + oc0 + c], a);
    }
}

// ----- encoder: x3 = [81][4][NIMG][32]; BN3 constants inline from acc3 -----
// r23 decomposition (nh-split, grid 512, 2A x 4B frags) + B staged in LDS:
// all 4 waves read identical ewb fragments -> stage cooperatively in 9-chunk
// phases (36KB, conv_tile's conflict-free layout).
__global__ __launch_bounds__(256) void enc_mfma(const bf16* __restrict__ x3,
        const bf16* __restrict__ ewb, const float* __restrict__ acc3,
        const float* __restrict__ gma, const float* __restrict__ bta,
        float* __restrict__ part) {
    __shared__ bf16 Bs[9 * 4 * 512];     // 36,864 B: 9 chunks x 4 nf x 512
    const int lin = blockIdx.x;
    const int xcd = lin & 7;
    const int slot = lin >> 3;           // 0..63
    const int igl = slot >> 3;           // 0..7
    const int combo = slot & 7;
    const int ks = combo >> 1, nh = combo & 1;
    const int ig = xcd * 8 + igl;        // 64 groups of 128 imgs
    const int tid = threadIdx.x;
    const int lane = tid & 63, wv = tid >> 6;
    const int m = lane & 15, quad = lane >> 4;
    const long img0 = (long)ig * 128 + wv * 32;
    constexpr size_t CSTRIDE = (size_t)NIMG * 32;

    // BN3 per-lane constants from raw stats (stats_fin folded in)
    const float inv = 1.0f / (8192.0f * 81.0f);
    float scv[4][8], shv[4][8];
#pragma unroll
    for (int cc = 0; cc < 4; cc++)
#pragma unroll
        for (int j = 0; j < 8; j++) {
            int ci = cc * 32 + quad * 8 + j;
            float mean = acc3[ci] * inv;
            float var = acc3[128 + ci] * inv - mean * mean;
            float sc = rsqrtf(var + 1e-5f) * gma[ci];
            scv[cc][j] = sc;
            shv[cc][j] = bta[ci] - mean * sc;
        }

    f32x4 acc[2][4];
#pragma unroll
    for (int ms = 0; ms < 2; ms++)
#pragma unroll
        for (int nf = 0; nf < 4; nf++) {
            acc[ms][nf][0]=0.f; acc[ms][nf][1]=0.f; acc[ms][nf][2]=0.f; acc[ms][nf][3]=0.f;
        }
    const bf16* ab[2];
#pragma unroll
    for (int ms = 0; ms < 2; ms++)
        ab[ms] = x3 + (size_t)(ks * 81) * CSTRIDE + (img0 + ms * 16 + m) * 32 + quad * 8;
    const bf16* bsl = &Bs[lane * 8];

    for (int ph = 0; ph < 9; ph++) {
        __syncthreads();
        // stage 9 chunks x 4 nf x 1KB cooperatively (each elem loaded once/block)
        for (int i = tid; i < 9 * 4 * 64; i += 256) {
            int l2 = i & 63, nf = (i >> 6) & 3, cl = i >> 8;
            int mm = l2 & 15, qq = l2 >> 4;
            *(bf16x8*)(&Bs[(size_t)i * 8]) =
                *(const bf16x8*)(ewb + (size_t)(nh * 64 + nf * 16 + mm) * FLAT
                                 + (ks * 81 + ph * 9 + cl) * 32 + qq * 8);
        }
        __syncthreads();
#pragma unroll
        for (int cl = 0; cl < 9; cl++) {
            const int c = ph * 9 + cl;
            const int cc = (ks + c) & 3;
            bf16x8 Ac[2], Bc[4];
#pragma unroll
            for (int ms = 0; ms < 2; ms++) {
                bf16x8 raw = *(const bf16x8*)(ab[ms] + (size_t)c * CSTRIDE);
                Ac[ms] = bn8(raw, scv[cc], shv[cc]);
            }
#pragma unroll
            for (int nf = 0; nf < 4; nf++)
                Bc[nf] = *(const bf16x8*)(bsl + (cl * 4 + nf) * 512);
#pragma unroll
            for (int nf = 0; nf < 4; nf++)
#pragma unroll
                for (int ms = 0; ms < 2; ms++)
                    acc[ms][nf] = __builtin_amdgcn_mfma_f32_16x16x32_bf16(Ac[ms], Bc[nf], acc[ms][nf], 0, 0, 0);
        }
    }

    float* pp = part + (size_t)ks * (NIMG * 128) + (img0 + quad * 4) * 128 + nh * 64 + m;
#pragma unroll
    for (int ms = 0; ms < 2; ms++)
#pragma unroll
        for (int nf = 0; nf < 4; nf++)
#pragma unroll
            for (int r = 0; r < 4; r++)
                pp[(ms * 16 + r) * 128 + nf * 16] = acc[ms][nf][r];
}

// ---- k-split reduce + bias + transpose: xT[b][f][n] = sum parts + encb ----
__global__ void enc_reduce(const float* __restrict__ part, const float* __restrict__ encb,
                           float* __restrict__ xT) {
    int i = blockIdx.x * 256 + threadIdx.x;
    const int NP = NIMG * 128;
    if (i < NP) {
        float v = part[i] + part[NP + i] + part[2 * NP + i] + part[3 * NP + i] + encb[i & 127];
        int img = i >> 7, f = i & 127;
        xT[(size_t)(img >> 7) * 16384 + f * 128 + (img & 127)] = v;
    }
}

// Y[b] = A[b] (128x128) @ S[b] (128x128); 16-row tiles, grid (8,64)
__global__ __launch_bounds__(256) void mm_xs(const float* __restrict__ A,
        const float* __restrict__ S, float* __restrict__ Y) {
    __shared__ __align__(16) float Sc[32 * 132];
    __shared__ float Acm[16 * 33];
    int b = blockIdx.y, f0 = blockIdx.x * 16;
    int t = threadIdx.x;
    int fl = t & 15, mg = t >> 4;        // fl: row 0..15, mg: col-group of 8
    const float* Ab = A + (size_t)b * 16384;
    const float* Sb = S + (size_t)b * 16384;
    float acc[8];
#pragma unroll
    for (int j = 0; j < 8; j++) acc[j] = 0.f;
    for (int nc = 0; nc < 128; nc += 32) {
#pragma unroll
        for (int r = 0; r < 4; r++) {
            int i4 = r * 256 + t;
            int nn = i4 >> 5, m4 = (i4 & 31) * 4;
            *(float4*)&Sc[nn * 132 + m4] = *(const float4*)&Sb[(size_t)(nc + nn) * 128 + m4];
        }
#pragma unroll
        for (int r = 0; r < 2; r++) {
            int i = r * 256 + t;
            int ff = i >> 5, nn = i & 31;
            Acm[ff * 33 + nn] = Ab[(size_t)(f0 + ff) * 128 + nc + nn];
        }
        __syncthreads();
#pragma unroll 4
        for (int nn = 0; nn < 32; nn++) {
            float a = Acm[fl * 33 + nn];
#pragma unroll
            for (int j = 0; j < 2; j++) {
                float4 s4 = *(const float4*)&Sc[nn * 132 + mg * 8 + j * 4];
                acc[j*4+0] = fmaf(a, s4.x, acc[j*4+0]);
                acc[j*4+1] = fmaf(a, s4.y, acc[j*4+1]);
                acc[j*4+2] = fmaf(a, s4.z, acc[j*4+2]);
                acc[j*4+3] = fmaf(a, s4.w, acc[j*4+3]);
            }
        }
        __syncthreads();
    }
    float* yb = Y + (size_t)b * 16384 + (size_t)(f0 + fl) * 128 + mg * 8;
    *(float4*)&yb[0] = make_float4(acc[0], acc[1], acc[2], acc[3]);
    *(float4*)&yb[4] = make_float4(acc[4], acc[5], acc[6], acc[7]);
}

// Out[b][g][n] = relu( sum_f W0[g,f]Z0 + W1 Z1 + W2 Z2 + bias[g] ); grid (8,64)
__global__ __launch_bounds__(256) void gf_combine(const float* __restrict__ Z0,
        const float* __restrict__ Z1, const float* __restrict__ Z2,
        const float* __restrict__ W, const float* __restrict__ bias,
        float* __restrict__ out) {
    __shared__ __align__(16) float Zc[32 * 132];
    __shared__ float Wc[16 * 33];
    int b = blockIdx.y, g0 = blockIdx.x * 16;
    int t = threadIdx.x;
    int gl = t & 15, mg = t >> 4;
    float acc[8];
    float bb = bias[g0 + gl];
#pragma unroll
    for (int j = 0; j < 8; j++) acc[j] = bb;
    const float* Zs[3] = {Z0 + (size_t)b * 16384, Z1 + (size_t)b * 16384, Z2 + (size_t)b * 16384};
    for (int j3 = 0; j3 < 3; j3++) {
        const float* Zb = Zs[j3];
        const float* Wj = W + j3 * 16384;
        for (int fc = 0; fc < 128; fc += 32) {
#pragma unroll
            for (int r = 0; r < 4; r++) {
                int i4 = r * 256 + t;
                int ff = i4 >> 5, m4 = (i4 & 31) * 4;
                *(float4*)&Zc[ff * 132 + m4] = *(const float4*)&Zb[(size_t)(fc + ff) * 128 + m4];
            }
#pragma unroll
            for (int r = 0; r < 2; r++) {
                int i = r * 256 + t;
                int gg = i >> 5, ff = i & 31;
                Wc[gg * 33 + ff] = Wj[(size_t)(g0 + gg) * 128 + fc + ff];
            }
            __syncthreads();
#pragma unroll 4
            for (int ff = 0; ff < 32; ff++) {
                float w = Wc[gl * 33 + ff];
#pragma unroll
                for (int j = 0; j < 2; j++) {
                    float4 z4 = *(const float4*)&Zc[ff * 132 + mg * 8 + j * 4];
                    acc[j*4+0] = fmaf(w, z4.x, acc[j*4+0]);
                    acc[j*4+1] = fmaf(w, z4.y, acc[j*4+1]);
                    acc[j*4+2] = fmaf(w, z4.z, acc[j*4+2]);
                    acc[j*4+3] = fmaf(w, z4.w, acc[j*4+3]);
                }
            }
            __syncthreads();
        }
    }
    float* ob = out + (size_t)b * 16384 + (size_t)(g0 + gl) * 128 + mg * 8;
    *(float4*)&ob[0] = make_float4(fmaxf(acc[0], 0.f), fmaxf(acc[1], 0.f),
                                   fmaxf(acc[2], 0.f), fmaxf(acc[3], 0.f));
    *(float4*)&ob[4] = make_float4(fmaxf(acc[4], 0.f), fmaxf(acc[5], 0.f),
                                   fmaxf(acc[6], 0.f), fmaxf(acc[7], 0.f));
}

// logits[b,n,a] = sum_g X[b][g][n] * aw[a][g] + ab[a]
// grid (64, 4): block (b, qn) handles n in [qn*32, qn*32+32).
// 128 thr = 32 n x 4 g-chunks; LDS reduce; gs==0 writes + bias.
__global__ __launch_bounds__(128) void act_kernel(const float* __restrict__ X,
        const float* __restrict__ aw, const float* __restrict__ ab,
        float* __restrict__ out) {
    __shared__ float red[4][32][5];
    int b = blockIdx.x, qn = blockIdx.y;
    int t = threadIdx.x;
    int nl = t & 31, gs = t >> 5;
    int n = qn * 32 + nl;
    float acc[5];
#pragma unroll
    for (int a = 0; a < 5; a++) acc[a] = 0.f;
    const float* xb = X + (size_t)b * 16384 + (size_t)gs * 32 * 128 + n;
#pragma unroll 4
    for (int g = 0; g < 32; g++) {
        float v = xb[(size_t)g * 128];
#pragma unroll
        for (int a = 0; a < 5; a++) acc[a] = fmaf(v, aw[a * 128 + gs * 32 + g], acc[a]);
    }
#pragma unroll
    for (int a = 0; a < 5; a++) red[gs][nl][a] = acc[a];
    __syncthreads();
    if (gs == 0) {
        float* ob = out + ((size_t)b * 128 + n) * 5;
#pragma unroll
        for (int a = 0; a < 5; a++)
            ob[a] = red[0][nl][a] + red[1][nl][a] + red[2][nl][a] + red[3][nl][a] + ab[a];
    }
}

// ---------------------------------------------------------------------------
extern "C" void kernel_launch(void* const* d_in, const int* in_sizes, int n_in,
                              void* d_out, int out_size, void* d_ws, size_t ws_size,
                              hipStream_t stream) {
    const float* states = (const float*)d_in[0];
    const float* gso    = (const float*)d_in[1];
    const float* c1w  = (const float*)d_in[2];
    const float* c1b  = (const float*)d_in[3];
    const float* c1g  = (const float*)d_in[4];
    const float* c1be = (const float*)d_in[5];
    const float* c2w  = (const float*)d_in[6];
    const float* c2b  = (const float*)d_in[7];
    const float* c2g  = (const float*)d_in[8];
    const float* c2be = (const float*)d_in[9];
    const float* c3w  = (const float*)d_in[10];
    const float* c3b  = (const float*)d_in[11];
    const float* c3g  = (const float*)d_in[12];
    const float* c3be = (const float*)d_in[13];
    const float* encw = (const float*)d_in[14];
    const float* encb = (const float*)d_in[15];
    const float* g1w  = (const float*)d_in[16];
    const float* g1b  = (const float*)d_in[17];
    const float* g2w  = (const float*)d_in[18];
    const float* g2b  = (const float*)d_in[19];
    const float* aw   = (const float*)d_in[20];
    const float* ab   = (const float*)d_in[21];
    float* out = (float*)d_out;
    char* ws = (char*)d_ws;

    size_t o = 0;
    auto take = [&](size_t bytes) { size_t r = o; o += (bytes + 255) & ~(size_t)255; return r; };
    const size_t o_x3  = take((size_t)81 * 4 * NIMG * 32 * 2);   // 169,869,312
    const size_t o_x2  = take((size_t)81 * 2 * NIMG * 32 * 2);   //  84,934,656
    const size_t o_w1t = take(27 * 32 * 4);
    const size_t o_w2m = take(64 * 288 * 2);
    const size_t o_w3m = take(128 * 576 * 2);
    const size_t o_acc = take(448 * 4);
    if (ws_size < o) {
        fill_sentinel<<<(out_size + 255) / 256, 256, 0, stream>>>(out, out_size);
        return;
    }

    const size_t o_x1 = o_x3;                       // x1 (42.5MB) at head of x3 region
    const size_t o_ewb  = o_x2;                     // 2,654,208 (aliases dead x2)
    const size_t o_part = o_x2 + 2654208;           // 16,777,216 (4 k-split partials)
    const size_t o_xT   = o_part + 16777216;
    const size_t o_y1   = o_xT + 4194304;
    const size_t o_y2   = o_y1 + 4194304;
    const size_t o_G1   = o_y2 + 4194304;
    const size_t o_G2   = o_G1 + 4194304;           // ends ~40MB < 85MB region

    bf16* x1 = (bf16*)(ws + o_x1);
    bf16* x2 = (bf16*)(ws + o_x2);
    bf16* x3 = (bf16*)(ws + o_x3);
    float* w1t = (float*)(ws + o_w1t);
    bf16* w2m = (bf16*)(ws + o_w2m);
    bf16* w3m = (bf16*)(ws + o_w3m);
    float* acc1 = (float*)(ws + o_acc);
    float* acc2 = acc1 + 64;
    float* acc3 = acc1 + 192;
    bf16* ewb = (bf16*)(ws + o_ewb);
    float* partp = (float*)(ws + o_part);
    float* xT = (float*)(ws + o_xT);
    float* y1 = (float*)(ws + o_y1);
    float* y2 = (float*)(ws + o_y2);
    float* xG1 = (float*)(ws + o_G1);
    float* xG2 = (float*)(ws + o_G2);

    hipMemsetAsync(ws + o_acc, 0, 448 * 4, stream);
    prep_w<<<128, 256, 0, stream>>>(c1w, c2w, c3w, w1t, w2m, w3m);

    conv1_kernel<<<2048, 128, 0, stream>>>(states, w1t, c1b, x1, acc1);
    bnrelu_k<1><<<4096, 256, 0, stream>>>(x1, acc1, c1g, c1be, 81 * 1 * NIMG * 32 / 8);

    conv_tile<32, 64, 1><<<2592, 256, 0, stream>>>(x1, w2m, c2b, x2, acc2);
    bnrelu_k<2><<<4096, 256, 0, stream>>>(x2, acc2, c2g, c2be, 81 * 2 * NIMG * 32 / 8);

    conv_tile<64, 128, 1><<<2592, 256, 0, stream>>>(x2, w3m, c3b, x3, acc3);

    prep_enc<<<2048, 256, 0, stream>>>(encw, ewb);
    enc_mfma<<<512, 256, 0, stream>>>(x3, ewb, acc3, c3g, c3be, partp);
    enc_reduce<<<4096, 256, 0, stream>>>(partp, encb, xT);

    mm_xs<<<dim3(8, 64), 256, 0, stream>>>(xT, gso, y1);
    mm_xs<<<dim3(8, 64), 256, 0, stream>>>(y1, gso, y2);
    gf_combine<<<dim3(8, 64), 256, 0, stream>>>(xT, y1, y2, g1w, g1b, xG1);

    mm_xs<<<dim3(8, 64), 256, 0, stream>>>(xG1, gso, y1);
    mm_xs<<<dim3(8, 64), 256, 0, stream>>>(y1, gso, y2);
    gf_combine<<<dim3(8, 64), 256, 0, stream>>>(xG1, y1, y2, g2w, g2b, xG2);

    act_kernel<<<dim3(64, 4), 128, 0, stream>>>(xG2, aw, ab, out);
}

// Round 18
// 642.903 us; speedup vs baseline: 1.0630x; 1.0009x over previous
//
#include <hip/hip_runtime.h>
#include <hip/hip_bf16.h>
#include <stdint.h>

// ---------------------------------------------------------------------------
// Network_60163901882451 — round 32: lock in r31 (best measured, 643.5us).
// Session ladder: 751 -> 700 (BN hoist) -> 669 (enc revert + stats folds +
// mm/gf retile) -> 650.5 (enc B-LDS staging) -> 643.5 (act parallelize).
// conv_tile MS=4/NF=8 confirmed local optimum (8 perturbation families all
// non-positive). Exact resubmit of the verified best configuration.
// ---------------------------------------------------------------------------

#define NIMG 8192
#define NPIX 81
#define FLAT 10368

typedef __hip_bfloat16 bf16;
typedef short bf16x8 __attribute__((ext_vector_type(8)));
typedef float f32x4 __attribute__((ext_vector_type(4)));

__device__ __forceinline__ float bflo(unsigned u) { return __uint_as_float(u << 16); }
__device__ __forceinline__ float bfhi(unsigned u) { return __uint_as_float(u & 0xffff0000u); }
__device__ __forceinline__ unsigned short f2bf(float f) {
    unsigned u = __float_as_uint(f);
    return (unsigned short)((u + 0x7fff + ((u >> 16) & 1)) >> 16);
}

// BN+relu on a bf16x8 fragment; sc/sh are per-element (ci-indexed) registers
__device__ __forceinline__ bf16x8 bn8(bf16x8 a, const float* sc, const float* sh) {
    union U { bf16x8 v; unsigned u[4]; } in, out;
    in.v = a;
#pragma unroll
    for (int d = 0; d < 4; d++) {
        float lo = fmaxf(fmaf(bflo(in.u[d]), sc[2 * d],     sh[2 * d]),     0.f);
        float hi = fmaxf(fmaf(bfhi(in.u[d]), sc[2 * d + 1], sh[2 * d + 1]), 0.f);
        out.u[d] = (unsigned)f2bf(lo) | ((unsigned)f2bf(hi) << 16);
    }
    return out.v;
}

__global__ void fill_sentinel(float* __restrict__ out, int n) {
    int i = blockIdx.x * 256 + threadIdx.x;
    if (i < n) out[i] = 1.0e9f;   // ws_size-too-small signature
}

// ---------------- weight preps ---------------------------------------------
__global__ void prep_w(const float* __restrict__ c1w, const float* __restrict__ c2w,
                       const float* __restrict__ c3w,
                       float* __restrict__ w1t, bf16* __restrict__ w2m,
                       bf16* __restrict__ w3m) {
    int i0 = blockIdx.x * blockDim.x + threadIdx.x;
    int stride = gridDim.x * blockDim.x;
    for (int i = i0; i < 27 * 32; i += stride) w1t[i] = c1w[(i & 31) * 27 + (i >> 5)];
    for (int i = i0; i < 64 * 288; i += stride) {
        int oc = i / 288, r = i - oc * 288, t = r >> 5, ci = r & 31;
        w2m[i] = __float2bfloat16(c2w[oc * 288 + ci * 9 + t]);
    }
    for (int i = i0; i < 128 * 576; i += stride) {
        int oc = i / 576, r = i - oc * 576, t = r >> 6, ci = r & 63;
        w3m[i] = __float2bfloat16(c3w[oc * 576 + ci * 9 + t]);
    }
}

// ewb[e][(px*4+cc)*32+c32] = encw[e][(cc*32+c32)*81+px]  (K-chunk order)
__global__ void prep_enc(const float* __restrict__ encw, bf16* __restrict__ ewb) {
    int i0 = blockIdx.x * blockDim.x + threadIdx.x;
    int stride = gridDim.x * blockDim.x;
    for (int i = i0; i < 128 * FLAT; i += stride) {
        int e = i / FLAT, r = i - e * FLAT;
        int kk = r >> 5, c32 = r & 31;
        int px = kk >> 2, cc = kk & 3;
        ewb[i] = __float2bfloat16(encw[(size_t)e * FLAT + (cc * 32 + c32) * 81 + px]);
    }
}

// --------- one-shot BN+ReLU over a raw activation buffer (in place) --------
// layout [px][ch][img][32]; BN constants computed in-block from raw stats.
template <int NCH>
__global__ __launch_bounds__(256) void bnrelu_k(bf16* __restrict__ x,
        const float* __restrict__ accp, const float* __restrict__ gma,
        const float* __restrict__ bta, int n8) {
    __shared__ float stl[2][NCH * 32];
    int t = threadIdx.x;
    if (t < NCH * 32) {
        const float inv = 1.0f / (8192.0f * 81.0f);
        float mean = accp[t] * inv;
        float var = accp[NCH * 32 + t] * inv - mean * mean;
        float sc = rsqrtf(var + 1e-5f) * gma[t];
        stl[0][t] = sc;
        stl[1][t] = bta[t] - mean * sc;
    }
    __syncthreads();
    int i0 = blockIdx.x * 256 + t;
    int stride = gridDim.x * 256;
    for (int i = i0; i < n8; i += stride) {
        size_t base = (size_t)i * 8;
        int ch = (int)((base >> 18) & (unsigned)(NCH - 1));
        int c0 = ch * 32 + (int)(base & 31);
        float sc[8], sh[8];
#pragma unroll
        for (int j = 0; j < 8; j++) {
            sc[j] = stl[0][c0 + j];
            sh[j] = stl[1][c0 + j];
        }
        bf16x8 v = *(bf16x8*)(x + base);
        *(bf16x8*)(x + base) = bn8(v, sc, sh);
    }
}

// ---------------- conv1 (direct fp32; fused stats; [px][img][32] out) ------
__device__ __forceinline__ void load_row(const float* __restrict__ p, float* r) {
    float4 a = *(const float4*)p;
    float4 b = *(const float4*)(p + 4);
    float4 c = *(const float4*)(p + 8);
    r[0]=a.x; r[1]=a.y; r[2]=a.z;  r[3]=a.w;
    r[4]=b.x; r[5]=b.y; r[6]=b.z;  r[7]=b.w;
    r[8]=c.x; r[9]=c.y; r[10]=c.z; r[11]=c.w;
}

__device__ __forceinline__ void conv_body(const float* __restrict__ inp,
                                          const float* __restrict__ wv, float* acc) {
    float rb[3][12];
    load_row(inp, rb[0]);
    load_row(inp + 12, rb[1]);
#pragma unroll
    for (int oy = 0; oy < 9; oy++) {
        load_row(inp + (oy + 2) * 12, rb[(oy + 2) % 3]);
#pragma unroll
        for (int ky = 0; ky < 3; ky++) {
            const float* r = rb[(oy + ky) % 3];
#pragma unroll
            for (int ox = 0; ox < 9; ox++) {
                float s = acc[oy * 9 + ox];
                s = fmaf(r[ox + 0], wv[ky * 3 + 0], s);
                s = fmaf(r[ox + 1], wv[ky * 3 + 1], s);
                s = fmaf(r[ox + 2], wv[ky * 3 + 2], s);
                acc[oy * 9 + ox] = s;
            }
        }
    }
}

__global__ __launch_bounds__(128) void conv1_kernel(const float* __restrict__ xin,
        const float* __restrict__ wt, const float* __restrict__ bias,
        bf16* __restrict__ xout, float* __restrict__ sacc) {
    __shared__ __align__(16) float lds[4 * 3 * 132];
    __shared__ float Sl[128], Ql[128];
    int t = threadIdx.x;
    int img0 = blockIdx.x * 4;
    for (int i = t; i < 4 * 3 * 132; i += 128) lds[i] = 0.f;
    __syncthreads();
    const float* src = xin + (size_t)img0 * 243;
    for (int i = t; i < 4 * 243; i += 128) {
        int il = i / 243, rem = i - il * 243;
        int ci = rem / 81, px = rem - ci * 81;
        lds[(il * 3 + ci) * 132 + (px / 9 + 1) * 12 + (px % 9) + 1] = src[i];
    }
    __syncthreads();
    int oc = t & 31, il = t >> 5;
    const float* base = lds + il * 3 * 132;
    float acc[81];
    float bb = bias[oc];
#pragma unroll
    for (int i = 0; i < 81; i++) acc[i] = bb;
#pragma unroll
    for (int ci = 0; ci < 3; ci++) {
        float wv[9];
#pragma unroll
        for (int k = 0; k < 9; k++) wv[k] = wt[(ci * 9 + k) * 32 + oc];
        conv_body(base + ci * 132, wv, acc);
    }
    // out: [px][img][32]
    bf16* dst = xout + (size_t)(img0 + il) * 32 + oc;
    const size_t PXS = (size_t)NIMG * 32;
    float s = 0.f, q = 0.f;
#pragma unroll
    for (int p = 0; p < 81; p++) {
        float v = acc[p];
        s += v; q = fmaf(v, v, q);
        dst[p * PXS] = __float2bfloat16(v);
    }
    Sl[il * 32 + oc] = s;
    Ql[il * 32 + oc] = q;
    __syncthreads();
    if (t < 32)
        atomicAdd(&sacc[t], Sl[t] + Sl[32 + t] + Sl[64 + t] + Sl[96 + t]);
    else if (t < 64) {
        int c = t - 32;
        atomicAdd(&sacc[32 + c], Ql[c] + Ql[32 + c] + Ql[64 + c] + Ql[96 + c]);
    }
}

// ------- LDS-staged MFMA conv, pre-BN'd inputs, fused out-stats ------------
// xin: BN+ReLU'd bf16 [81][NCH][NIMG][32]; wm: bf16 [oc][9tap][CI];
// out RAW bf16 [81][NCHO][NIMG][32].  (r20 structure — best measured.)
template <int CI, int COT, int OCS>
__global__ __launch_bounds__(256, (CI == 64) ? 2 : 4) void conv_tile(
        const bf16* __restrict__ xin,
        const bf16* __restrict__ wm, const float* __restrict__ bias,
        bf16* __restrict__ xout, float* __restrict__ sacc) {
    constexpr int NCH = CI / 32;
    constexpr int NCHO = COT / 32;
    constexpr int NOC = COT / OCS;         // oc per block
    constexpr int NF = NOC / 16;           // oc fragments per block
    constexpr int LNF = (NF == 8) ? 3 : 2;
    constexpr int ROW = 9 * CI;
    constexpr int STEPS = 9 * NCH;
    constexpr int PHASES = STEPS / 9;      // conv2: 1, conv3: 2
    constexpr int HS = STEPS / PHASES;     // 9 steps per phase
    constexpr size_t CSTRIDE = (size_t)NIMG * 32;   // one (px,ch) slot
    __shared__ bf16 Bs[HS * NF * 64 * 8];
    __shared__ float Ss[2][4][NOC];

    const int lin = blockIdx.x;
    const int xcd = lin & 7;
    const int slot = lin >> 3;
    constexpr int PSL = 81 * OCS;
    const int igl = slot / PSL;
    const int rem = slot - igl * PSL;
    const int p = rem / OCS;
    const int ob = rem - p * OCS;
    const int ig = xcd * 4 + igl;          // 32 groups of 256 imgs
    const int oc0 = ob * NOC;
    const int py = p / 9, pxx = p - py * 9;
    const int tid = threadIdx.x;
    const int lane = tid & 63, wv = tid >> 6;
    const int m = lane & 15, quad = lane >> 4;
    const long img0 = (long)ig * 256 + wv * 64;

    int qt[9]; bool vt[9];
#pragma unroll
    for (int t = 0; t < 9; t++) {
        int iy = py + t / 3 - 1, ix = pxx + (t % 3) - 1;
        vt[t] = ((unsigned)iy < 9u) && ((unsigned)ix < 9u);
        qt[t] = vt[t] ? iy * 9 + ix : p;   // clamped safe address
    }

    f32x4 acc[4][NF];
#pragma unroll
    for (int nf = 0; nf < NF; nf++) {
        float bb = bias[oc0 + nf * 16 + m];
#pragma unroll
        for (int ms = 0; ms < 4; ms++) {
            acc[ms][nf][0] = bb; acc[ms][nf][1] = bb;
            acc[ms][nf][2] = bb; acc[ms][nf][3] = bb;
        }
    }
    // A base: [px][ch][img][32] -> frag = contiguous 1KB per wave
    const bf16* ab[4];
#pragma unroll
    for (int ms = 0; ms < 4; ms++)
        ab[ms] = xin + (img0 + ms * 16 + m) * 32 + quad * 8;

    const bf16* bsl = &Bs[lane * 8];

#pragma unroll
    for (int ph = 0; ph < PHASES; ph++) {
        __syncthreads();
        for (int i = tid; i < HS * NF * 64; i += 256) {
            int l2 = i & 63, nf = (i >> 6) & (NF - 1), sl = i >> (6 + LNF);
            int s = ph * HS + sl;
            int t = s / NCH, ch = s - t * NCH;
            int mm = l2 & 15, qq = l2 >> 4;
            *(bf16x8*)(&Bs[(size_t)i * 8]) =
                *(const bf16x8*)(wm + (size_t)(oc0 + nf * 16 + mm) * ROW + t * CI + ch * 32 + qq * 8);
        }
        __syncthreads();
#pragma unroll
        for (int sl = 0; sl < HS; sl++) {
            const int s = ph * HS + sl;
            const int t = s / NCH, ch = s - t * NCH;
            if (vt[t]) {                     // block-uniform: skip padding taps
                bf16x8 bfr[NF];
#pragma unroll
                for (int nf = 0; nf < NF; nf++)
                    bfr[nf] = *(const bf16x8*)(bsl + (sl * NF + nf) * 512);
                bf16x8 a[4];
#pragma unroll
                for (int ms = 0; ms < 4; ms++)
                    a[ms] = *(const bf16x8*)(ab[ms] + (size_t)(qt[t] * NCH + ch) * CSTRIDE);
#pragma unroll
                for (int ms = 0; ms < 4; ms++) {
#pragma unroll
                    for (int nf = 0; nf < NF; nf++)
                        acc[ms][nf] = __builtin_amdgcn_mfma_f32_16x16x32_bf16(a[ms], bfr[nf], acc[ms][nf], 0, 0, 0);
                }
            }
        }
    }

    // stores: out[p][chO][img][32]; oc = oc0 + nf*16 + m -> chO = oc0/32+(nf>>1)
    const int och = oc0 >> 5;
#pragma unroll
    for (int ms = 0; ms < 4; ms++)
#pragma unroll
        for (int nf = 0; nf < NF; nf++) {
            bf16* orow = xout
                + (((size_t)p * NCHO + och + (nf >> 1)) * NIMG + img0 + ms * 16 + quad * 4) * 32
                + (nf & 1) * 16 + m;
#pragma unroll
            for (int r = 0; r < 4; r++)
                orow[r * 32] = __float2bfloat16(acc[ms][nf][r]);
        }

    // fused BN stats: per-oc sum / sumsq over this block's outputs
    float ssum[NF], sq[NF];
#pragma unroll
    for (int nf = 0; nf < NF; nf++) {
        float s = 0.f, q = 0.f;
#pragma unroll
        for (int ms = 0; ms < 4; ms++)
#pragma unroll
            for (int r = 0; r < 4; r++) {
                float v = acc[ms][nf][r];
                s += v; q = fmaf(v, v, q);
            }
        s += __shfl_xor(s, 16); s += __shfl_xor(s, 32);
        q += __shfl_xor(q, 16); q += __shfl_xor(q, 32);
        ssum[nf] = s; sq[nf] = q;
    }
    if (lane < 16) {
#pragma unroll
        for (int nf = 0; nf < NF; nf++) {
            Ss[0][wv][nf * 16 + lane] = ssum[nf];
            Ss[1][wv][nf * 16 + lane] = sq[nf];
        }
    }
    __syncthreads();
    if (tid < NOC) {
        float a = Ss[0][0][tid] + Ss[0][1][tid] + Ss[0][2][tid] + Ss[0][3][tid];
        atomicAdd(&sacc[oc0 + tid], a);
    } else if (tid < 2 * NOC) {
        int c = tid - NOC;
        float a = Ss[1][0][c] + Ss[1][1][c] + Ss[1][2][c] + Ss[1][3][c];
        atomicAdd(&sacc[COT + oc0 + c], a);
    }
}

// ----- encoder: x3 = [81][4][NIMG][32]; BN3 constants inline from acc3 -----
// r23 decomposition (nh-split, grid 512, 2A x 4B frags) + B staged in LDS:
// all 4 waves read identical ewb fragments -> stage cooperatively in 9-chunk
// phases (36KB, conv_tile's conflict-free layout).
__global__ __launch_bounds__(256) void enc_mfma(const bf16* __restrict__ x3,
        const bf16* __restrict__ ewb, const float* __restrict__ acc3,
        const float* __restrict__ gma, const float* __restrict__ bta,
        float* __restrict__ part) {
    __shared__ bf16 Bs[9 * 4 * 512];     // 36,864 B: 9 chunks x 4 nf x 512
    const int lin = blockIdx.x;
    const int xcd = lin & 7;
    const int slot = lin >> 3;           // 0..63
    const int igl = slot >> 3;           // 0..7
    const int combo = slot & 7;
    const int ks = combo >> 1, nh = combo & 1;
    const int ig = xcd * 8 + igl;        // 64 groups of 128 imgs
    const int tid = threadIdx.x;
    const int lane = tid & 63, wv = tid >> 6;
    const int m = lane & 15, quad = lane >> 4;
    const long img0 = (long)ig * 128 + wv * 32;
    constexpr size_t CSTRIDE = (size_t)NIMG * 32;

    // BN3 per-lane constants from raw stats (stats_fin folded in)
    const float inv = 1.0f / (8192.0f * 81.0f);
    float scv[4][8], shv[4][8];
#pragma unroll
    for (int cc = 0; cc < 4; cc++)
#pragma unroll
        for (int j = 0; j < 8; j++) {
            int ci = cc * 32 + quad * 8 + j;
            float mean = acc3[ci] * inv;
            float var = acc3[128 + ci] * inv - mean * mean;
            float sc = rsqrtf(var + 1e-5f) * gma[ci];
            scv[cc][j] = sc;
            shv[cc][j] = bta[ci] - mean * sc;
        }

    f32x4 acc[2][4];
#pragma unroll
    for (int ms = 0; ms < 2; ms++)
#pragma unroll
        for (int nf = 0; nf < 4; nf++) {
            acc[ms][nf][0]=0.f; acc[ms][nf][1]=0.f; acc[ms][nf][2]=0.f; acc[ms][nf][3]=0.f;
        }
    const bf16* ab[2];
#pragma unroll
    for (int ms = 0; ms < 2; ms++)
        ab[ms] = x3 + (size_t)(ks * 81) * CSTRIDE + (img0 + ms * 16 + m) * 32 + quad * 8;
    const bf16* bsl = &Bs[lane * 8];

    for (int ph = 0; ph < 9; ph++) {
        __syncthreads();
        // stage 9 chunks x 4 nf x 1KB cooperatively (each elem loaded once/block)
        for (int i = tid; i < 9 * 4 * 64; i += 256) {
            int l2 = i & 63, nf = (i >> 6) & 3, cl = i >> 8;
            int mm = l2 & 15, qq = l2 >> 4;
            *(bf16x8*)(&Bs[(size_t)i * 8]) =
                *(const bf16x8*)(ewb + (size_t)(nh * 64 + nf * 16 + mm) * FLAT
                                 + (ks * 81 + ph * 9 + cl) * 32 + qq * 8);
        }
        __syncthreads();
#pragma unroll
        for (int cl = 0; cl < 9; cl++) {
            const int c = ph * 9 + cl;
            const int cc = (ks + c) & 3;
            bf16x8 Ac[2], Bc[4];
#pragma unroll
            for (int ms = 0; ms < 2; ms++) {
                bf16x8 raw = *(const bf16x8*)(ab[ms] + (size_t)c * CSTRIDE);
                Ac[ms] = bn8(raw, scv[cc], shv[cc]);
            }
#pragma unroll
            for (int nf = 0; nf < 4; nf++)
                Bc[nf] = *(const bf16x8*)(bsl + (cl * 4 + nf) * 512);
#pragma unroll
            for (int nf = 0; nf < 4; nf++)
#pragma unroll
                for (int ms = 0; ms < 2; ms++)
                    acc[ms][nf] = __builtin_amdgcn_mfma_f32_16x16x32_bf16(Ac[ms], Bc[nf], acc[ms][nf], 0, 0, 0);
        }
    }

    float* pp = part + (size_t)ks * (NIMG * 128) + (img0 + quad * 4) * 128 + nh * 64 + m;
#pragma unroll
    for (int ms = 0; ms < 2; ms++)
#pragma unroll
        for (int nf = 0; nf < 4; nf++)
#pragma unroll
            for (int r = 0; r < 4; r++)
                pp[(ms * 16 + r) * 128 + nf * 16] = acc[ms][nf][r];
}

// ---- k-split reduce + bias + transpose: xT[b][f][n] = sum parts + encb ----
__global__ void enc_reduce(const float* __restrict__ part, const float* __restrict__ encb,
                           float* __restrict__ xT) {
    int i = blockIdx.x * 256 + threadIdx.x;
    const int NP = NIMG * 128;
    if (i < NP) {
        float v = part[i] + part[NP + i] + part[2 * NP + i] + part[3 * NP + i] + encb[i & 127];
        int img = i >> 7, f = i & 127;
        xT[(size_t)(img >> 7) * 16384 + f * 128 + (img & 127)] = v;
    }
}

// Y[b] = A[b] (128x128) @ S[b] (128x128); 16-row tiles, grid (8,64)
__global__ __launch_bounds__(256) void mm_xs(const float* __restrict__ A,
        const float* __restrict__ S, float* __restrict__ Y) {
    __shared__ __align__(16) float Sc[32 * 132];
    __shared__ float Acm[16 * 33];
    int b = blockIdx.y, f0 = blockIdx.x * 16;
    int t = threadIdx.x;
    int fl = t & 15, mg = t >> 4;        // fl: row 0..15, mg: col-group of 8
    const float* Ab = A + (size_t)b * 16384;
    const float* Sb = S + (size_t)b * 16384;
    float acc[8];
#pragma unroll
    for (int j = 0; j < 8; j++) acc[j] = 0.f;
    for (int nc = 0; nc < 128; nc += 32) {
#pragma unroll
        for (int r = 0; r < 4; r++) {
            int i4 = r * 256 + t;
            int nn = i4 >> 5, m4 = (i4 & 31) * 4;
            *(float4*)&Sc[nn * 132 + m4] = *(const float4*)&Sb[(size_t)(nc + nn) * 128 + m4];
        }
#pragma unroll
        for (int r = 0; r < 2; r++) {
            int i = r * 256 + t;
            int ff = i >> 5, nn = i & 31;
            Acm[ff * 33 + nn] = Ab[(size_t)(f0 + ff) * 128 + nc + nn];
        }
        __syncthreads();
#pragma unroll 4
        for (int nn = 0; nn < 32; nn++) {
            float a = Acm[fl * 33 + nn];
#pragma unroll
            for (int j = 0; j < 2; j++) {
                float4 s4 = *(const float4*)&Sc[nn * 132 + mg * 8 + j * 4];
                acc[j*4+0] = fmaf(a, s4.x, acc[j*4+0]);
                acc[j*4+1] = fmaf(a, s4.y, acc[j*4+1]);
                acc[j*4+2] = fmaf(a, s4.z, acc[j*4+2]);
                acc[j*4+3] = fmaf(a, s4.w, acc[j*4+3]);
            }
        }
        __syncthreads();
    }
    float* yb = Y + (size_t)b * 16384 + (size_t)(f0 + fl) * 128 + mg * 8;
    *(float4*)&yb[0] = make_float4(acc[0], acc[1], acc[2], acc[3]);
    *(float4*)&yb[4] = make_float4(acc[4], acc[5], acc[6], acc[7]);
}

// Out[b][g][n] = relu( sum_f W0[g,f]Z0 + W1 Z1 + W2 Z2 + bias[g] ); grid (8,64)
__global__ __launch_bounds__(256) void gf_combine(const float* __restrict__ Z0,
        const float* __restrict__ Z1, const float* __restrict__ Z2,
        const float* __restrict__ W, const float* __restrict__ bias,
        float* __restrict__ out) {
    __shared__ __align__(16) float Zc[32 * 132];
    __shared__ float Wc[16 * 33];
    int b = blockIdx.y, g0 = blockIdx.x * 16;
    int t = threadIdx.x;
    int gl = t & 15, mg = t >> 4;
    float acc[8];
    float bb = bias[g0 + gl];
#pragma unroll
    for (int j = 0; j < 8; j++) acc[j] = bb;
    const float* Zs[3] = {Z0 + (size_t)b * 16384, Z1 + (size_t)b * 16384, Z2 + (size_t)b * 16384};
    for (int j3 = 0; j3 < 3; j3++) {
        const float* Zb = Zs[j3];
        const float* Wj = W + j3 * 16384;
        for (int fc = 0; fc < 128; fc += 32) {
#pragma unroll
            for (int r = 0; r < 4; r++) {
                int i4 = r * 256 + t;
                int ff = i4 >> 5, m4 = (i4 & 31) * 4;
                *(float4*)&Zc[ff * 132 + m4] = *(const float4*)&Zb[(size_t)(fc + ff) * 128 + m4];
            }
#pragma unroll
            for (int r = 0; r < 2; r++) {
                int i = r * 256 + t;
                int gg = i >> 5, ff = i & 31;
                Wc[gg * 33 + ff] = Wj[(size_t)(g0 + gg) * 128 + fc + ff];
            }
            __syncthreads();
#pragma unroll 4
            for (int ff = 0; ff < 32; ff++) {
                float w = Wc[gl * 33 + ff];
#pragma unroll
                for (int j = 0; j < 2; j++) {
                    float4 z4 = *(const float4*)&Zc[ff * 132 + mg * 8 + j * 4];
                    acc[j*4+0] = fmaf(w, z4.x, acc[j*4+0]);
                    acc[j*4+1] = fmaf(w, z4.y, acc[j*4+1]);
                    acc[j*4+2] = fmaf(w, z4.z, acc[j*4+2]);
                    acc[j*4+3] = fmaf(w, z4.w, acc[j*4+3]);
                }
            }
            __syncthreads();
        }
    }
    float* ob = out + (size_t)b * 16384 + (size_t)(g0 + gl) * 128 + mg * 8;
    *(float4*)&ob[0] = make_float4(fmaxf(acc[0], 0.f), fmaxf(acc[1], 0.f),
                                   fmaxf(acc[2], 0.f), fmaxf(acc[3], 0.f));
    *(float4*)&ob[4] = make_float4(fmaxf(acc[4], 0.f), fmaxf(acc[5], 0.f),
                                   fmaxf(acc[6], 0.f), fmaxf(acc[7], 0.f));
}

// logits[b,n,a] = sum_g X[b][g][n] * aw[a][g] + ab[a]
// grid (64, 4): block (b, qn) handles n in [qn*32, qn*32+32).
// 128 thr = 32 n x 4 g-chunks; LDS reduce; gs==0 writes + bias.
__global__ __launch_bounds__(128) void act_kernel(const float* __restrict__ X,
        const float* __restrict__ aw, const float* __restrict__ ab,
        float* __restrict__ out) {
    __shared__ float red[4][32][5];
    int b = blockIdx.x, qn = blockIdx.y;
    int t = threadIdx.x;
    int nl = t & 31, gs = t >> 5;
    int n = qn * 32 + nl;
    float acc[5];
#pragma unroll
    for (int a = 0; a < 5; a++) acc[a] = 0.f;
    const float* xb = X + (size_t)b * 16384 + (size_t)gs * 32 * 128 + n;
#pragma unroll 4
    for (int g = 0; g < 32; g++) {
        float v = xb[(size_t)g * 128];
#pragma unroll
        for (int a = 0; a < 5; a++) acc[a] = fmaf(v, aw[a * 128 + gs * 32 + g], acc[a]);
    }
#pragma unroll
    for (int a = 0; a < 5; a++) red[gs][nl][a] = acc[a];
    __syncthreads();
    if (gs == 0) {
        float* ob = out + ((size_t)b * 128 + n) * 5;
#pragma unroll
        for (int a = 0; a < 5; a++)
            ob[a] = red[0][nl][a] + red[1][nl][a] + red[2][nl][a] + red[3][nl][a] + ab[a];
    }
}

// ---------------------------------------------------------------------------
extern "C" void kernel_launch(void* const* d_in, const int* in_sizes, int n_in,
                              void* d_out, int out_size, void* d_ws, size_t ws_size,
                              hipStream_t stream) {
    const float* states = (const float*)d_in[0];
    const float* gso    = (const float*)d_in[1];
    const float* c1w  = (const float*)d_in[2];
    const float* c1b  = (const float*)d_in[3];
    const float* c1g  = (const float*)d_in[4];
    const float* c1be = (const float*)d_in[5];
    const float* c2w  = (const float*)d_in[6];
    const float* c2b  = (const float*)d_in[7];
    const float* c2g  = (const float*)d_in[8];
    const float* c2be = (const float*)d_in[9];
    const float* c3w  = (const float*)d_in[10];
    const float* c3b  = (const float*)d_in[11];
    const float* c3g  = (const float*)d_in[12];
    const float* c3be = (const float*)d_in[13];
    const float* encw = (const float*)d_in[14];
    const float* encb = (const float*)d_in[15];
    const float* g1w  = (const float*)d_in[16];
    const float* g1b  = (const float*)d_in[17];
    const float* g2w  = (const float*)d_in[18];
    const float* g2b  = (const float*)d_in[19];
    const float* aw   = (const float*)d_in[20];
    const float* ab   = (const float*)d_in[21];
    float* out = (float*)d_out;
    char* ws = (char*)d_ws;

    size_t o = 0;
    auto take = [&](size_t bytes) { size_t r = o; o += (bytes + 255) & ~(size_t)255; return r; };
    const size_t o_x3  = take((size_t)81 * 4 * NIMG * 32 * 2);   // 169,869,312
    const size_t o_x2  = take((size_t)81 * 2 * NIMG * 32 * 2);   //  84,934,656
    const size_t o_w1t = take(27 * 32 * 4);
    const size_t o_w2m = take(64 * 288 * 2);
    const size_t o_w3m = take(128 * 576 * 2);
    const size_t o_acc = take(448 * 4);
    if (ws_size < o) {
        fill_sentinel<<<(out_size + 255) / 256, 256, 0, stream>>>(out, out_size);
        return;
    }

    const size_t o_x1 = o_x3;                       // x1 (42.5MB) at head of x3 region
    const size_t o_ewb  = o_x2;                     // 2,654,208 (aliases dead x2)
    const size_t o_part = o_x2 + 2654208;           // 16,777,216 (4 k-split partials)
    const size_t o_xT   = o_part + 16777216;
    const size_t o_y1   = o_xT + 4194304;
    const size_t o_y2   = o_y1 + 4194304;
    const size_t o_G1   = o_y2 + 4194304;
    const size_t o_G2   = o_G1 + 4194304;           // ends ~40MB < 85MB region

    bf16* x1 = (bf16*)(ws + o_x1);
    bf16* x2 = (bf16*)(ws + o_x2);
    bf16* x3 = (bf16*)(ws + o_x3);
    float* w1t = (float*)(ws + o_w1t);
    bf16* w2m = (bf16*)(ws + o_w2m);
    bf16* w3m = (bf16*)(ws + o_w3m);
    float* acc1 = (float*)(ws + o_acc);
    float* acc2 = acc1 + 64;
    float* acc3 = acc1 + 192;
    bf16* ewb = (bf16*)(ws + o_ewb);
    float* partp = (float*)(ws + o_part);
    float* xT = (float*)(ws + o_xT);
    float* y1 = (float*)(ws + o_y1);
    float* y2 = (float*)(ws + o_y2);
    float* xG1 = (float*)(ws + o_G1);
    float* xG2 = (float*)(ws + o_G2);

    hipMemsetAsync(ws + o_acc, 0, 448 * 4, stream);
    prep_w<<<128, 256, 0, stream>>>(c1w, c2w, c3w, w1t, w2m, w3m);

    conv1_kernel<<<2048, 128, 0, stream>>>(states, w1t, c1b, x1, acc1);
    bnrelu_k<1><<<4096, 256, 0, stream>>>(x1, acc1, c1g, c1be, 81 * 1 * NIMG * 32 / 8);

    conv_tile<32, 64, 1><<<2592, 256, 0, stream>>>(x1, w2m, c2b, x2, acc2);
    bnrelu_k<2><<<4096, 256, 0, stream>>>(x2, acc2, c2g, c2be, 81 * 2 * NIMG * 32 / 8);

    conv_tile<64, 128, 1><<<2592, 256, 0, stream>>>(x2, w3m, c3b, x3, acc3);

    prep_enc<<<2048, 256, 0, stream>>>(encw, ewb);
    enc_mfma<<<512, 256, 0, stream>>>(x3, ewb, acc3, c3g, c3be, partp);
    enc_reduce<<<4096, 256, 0, stream>>>(partp, encb, xT);

    mm_xs<<<dim3(8, 64), 256, 0, stream>>>(xT, gso, y1);
    mm_xs<<<dim3(8, 64), 256, 0, stream>>>(y1, gso, y2);
    gf_combine<<<dim3(8, 64), 256, 0, stream>>>(xT, y1, y2, g1w, g1b, xG1);

    mm_xs<<<dim3(8, 64), 256, 0, stream>>>(xG1, gso, y1);
    mm_xs<<<dim3(8, 64), 256, 0, stream>>>(y1, gso, y2);
    gf_combine<<<dim3(8, 64), 256, 0, stream>>>(xG1, y1, y2, g2w, g2b, xG2);

    act_kernel<<<dim3(64, 4), 128, 0, stream>>>(xG2, aw, ab, out);
}